// Round 5
// baseline (579.650 us; speedup 1.0000x reference)
//
#include <hip/hip_runtime.h>
#include <hip/hip_bf16.h>
#include <math.h>

// Problem constants
#define Bc 2
#define Tc 2048
#define Cc 1024
#define Hc 16
#define Dc 64
// SCALE = 1/8, GAMMA = 8

typedef __attribute__((ext_vector_type(8))) short short8;   // 8 bf16 (4 VGPRs)
typedef __attribute__((ext_vector_type(4))) float f32x4;    // MFMA C/D frag

#define L2E 1.44269504088896f
#define SM_M 20.0f   // fixed softmax shift; |scores| << 20 (std ~0.3)

__device__ __forceinline__ short f2bf(float x) {
    unsigned u = __float_as_uint(x);
    u += 0x7fff + ((u >> 16) & 1);      // RNE
    return (short)(u >> 16);
}
__device__ __forceinline__ unsigned pack2bf(float a, float b) {
    unsigned ua = __float_as_uint(a); ua += 0x7fff + ((ua >> 16) & 1);
    unsigned ub = __float_as_uint(b); ub += 0x7fff + ((ub >> 16) & 1);
    return (ua >> 16) | (ub & 0xffff0000u);
}
__device__ __forceinline__ float softplusf(float a) {
    return fmaxf(a, 0.f) + log1pf(__expf(-fabsf(a)));
}

// ---------------------------------------------------------------------------
// bf16 MFMA GEMM (m97 recipe): C[M,N] = A[M,K] @ Bt[N,K]^T
// EPI 0: f32 out. EPI 1: bf16 out. EPI 2: moire QK epilogue — Bt rows are
// interleaved amp/phase pairs; adjacent-lane shfl pairs them, softplus+sincos
// writes q2 (blocks n0<2048, scale 1/8) or k2 (n0>=2048) in (B,H,T,128).
// ---------------------------------------------------------------------------
template <int EPI>
__global__ __launch_bounds__(256) void gemm_bt_mfma(
    const short* __restrict__ A, const short* __restrict__ Bt,
    float* __restrict__ Cf, short* __restrict__ Cb, short* __restrict__ Cb2,
    int M, int N, int K)
{
    __shared__ __attribute__((aligned(16))) short As[128 * 32];
    __shared__ __attribute__((aligned(16))) short Bs[128 * 32];

    const int tid = threadIdx.x;
    const int wave = tid >> 6, lane = tid & 63;
    const int quad = lane >> 4, c = lane & 15;
    const int wm = wave >> 1, wn = wave & 1;
    const int m0 = blockIdx.y * 128, n0 = blockIdx.x * 128;

    const int srow = lane >> 2;
    const int scol = (lane & 3) * 8;
    const short* Ag = A  + (size_t)(m0 + wave * 32 + srow) * K + scol;
    const short* Bg = Bt + (size_t)(n0 + wave * 32 + srow) * K + scol;
    short* AsW = As + (wave * 32) * 32;
    short* BsW = Bs + (wave * 32) * 32;

    f32x4 acc[4][4];
#pragma unroll
    for (int i = 0; i < 4; ++i)
#pragma unroll
        for (int j = 0; j < 4; ++j)
            acc[i][j] = (f32x4){0.f, 0.f, 0.f, 0.f};

    for (int k0 = 0; k0 < K; k0 += 32) {
        __syncthreads();
#pragma unroll
        for (int i = 0; i < 2; ++i) {
            __builtin_amdgcn_global_load_lds(
                (const __attribute__((address_space(1))) void*)(Ag + k0 + (size_t)i * 16 * K),
                (__attribute__((address_space(3))) void*)(AsW + i * 16 * 32), 16, 0, 0);
            __builtin_amdgcn_global_load_lds(
                (const __attribute__((address_space(1))) void*)(Bg + k0 + (size_t)i * 16 * K),
                (__attribute__((address_space(3))) void*)(BsW + i * 16 * 32), 16, 0, 0);
        }
        __syncthreads();

        short8 af[4], bf[4];
#pragma unroll
        for (int mt = 0; mt < 4; ++mt)
            af[mt] = *(const short8*)&As[(wm * 64 + mt * 16 + c) * 32 + quad * 8];
#pragma unroll
        for (int nt = 0; nt < 4; ++nt)
            bf[nt] = *(const short8*)&Bs[(wn * 64 + nt * 16 + c) * 32 + quad * 8];
#pragma unroll
        for (int mt = 0; mt < 4; ++mt)
#pragma unroll
            for (int nt = 0; nt < 4; ++nt)
                acc[mt][nt] = __builtin_amdgcn_mfma_f32_16x16x32_bf16(
                    af[mt], bf[nt], acc[mt][nt], 0, 0, 0);
    }

    if (EPI == 2) {
        const bool isK = (n0 >= 2048);
        short* dst = isK ? Cb2 : Cb;
        const float scl = isK ? 1.f : 0.125f;
#pragma unroll
        for (int mt = 0; mt < 4; ++mt) {
#pragma unroll
            for (int reg = 0; reg < 4; ++reg) {
                int m = m0 + wm * 64 + mt * 16 + quad * 4 + reg;
                int bb = m >> 11, tt = m & (Tc - 1);
#pragma unroll
                for (int nt = 0; nt < 4; ++nt) {
                    float a = acc[mt][nt][reg];
                    float other = __shfl_xor(a, 1);
                    int np = (n0 + wn * 64 + nt * 16 + c) & 2047;
                    int pi = np >> 1;
                    int hh = pi >> 6, dd = pi & 63;
                    size_t base = (((size_t)bb * Hc + hh) * Tc + tt) * 128 + dd;
                    if ((c & 1) == 0) {
                        float sp = softplusf(a);             // a = amp
                        dst[base] = f2bf(sp * __cosf(other) * scl);
                    } else {
                        float sp = softplusf(other);         // a = phase
                        dst[base + 64] = f2bf(sp * __sinf(a) * scl);
                    }
                }
            }
        }
    } else {
#pragma unroll
        for (int mt = 0; mt < 4; ++mt) {
#pragma unroll
            for (int reg = 0; reg < 4; ++reg) {
                size_t row = m0 + wm * 64 + mt * 16 + quad * 4 + reg;
#pragma unroll
                for (int nt = 0; nt < 4; ++nt) {
                    size_t col = n0 + wn * 64 + nt * 16 + c;
                    if (EPI == 1) Cb[row * N + col] = f2bf(acc[mt][nt][reg]);
                    else          Cf[row * N + col] = acc[mt][nt][reg];
                }
            }
        }
    }
}

// ---------------------------------------------------------------------------
__global__ __launch_bounds__(256) void xconv(const float* __restrict__ x,
                                             short* __restrict__ xb)
{
    int idx = blockIdx.x * 256 + threadIdx.x;
    float4 v = *(const float4*)&x[(size_t)idx * 4];
    short4 o = {f2bf(v.x), f2bf(v.y), f2bf(v.z), f2bf(v.w)};
    *(short4*)&xb[(size_t)idx * 4] = o;
}

// ---------------------------------------------------------------------------
// Merged Wq|Wk -> interleaved-transposed bf16 Bt (4096 x 1024).
// Dest row for source col n (within half): 2*(n & 1023) + (n >> 10).
// grid (2048/64, 1024/64, 2); z picks Wq (rows 0..2047) vs Wk (2048..4095).
// ---------------------------------------------------------------------------
__global__ __launch_bounds__(256) void wtrans_qk(const float* __restrict__ Wq,
                                                 const float* __restrict__ Wk,
                                                 short* __restrict__ Bt)
{
    __shared__ short tile[64][80];
    const int n0 = blockIdx.x * 64, k0 = blockIdx.y * 64;
    const int half = blockIdx.z;
    const float* W = half ? Wk : Wq;
    const int tid = threadIdx.x;
#pragma unroll
    for (int i = 0; i < 4; ++i) {
        int e = i * 256 + tid;
        int k = e >> 4, n4 = (e & 15) * 4;
        float4 v = *(const float4*)&W[(size_t)(k0 + k) * 2048 + n0 + n4];
        tile[k][n4]     = f2bf(v.x);
        tile[k][n4 + 1] = f2bf(v.y);
        tile[k][n4 + 2] = f2bf(v.z);
        tile[k][n4 + 3] = f2bf(v.w);
    }
    __syncthreads();
#pragma unroll
    for (int i = 0; i < 16; ++i) {
        int e = i * 256 + tid;
        int n = e >> 6, k = e & 63;
        int ng = n0 + n;
        int nrow = half * 2048 + 2 * (ng & 1023) + (ng >> 10);
        Bt[(size_t)nrow * Cc + k0 + k] = tile[k][n];
    }
}

// ---------------------------------------------------------------------------
// Merged Wv|Wo transpose-convert: grid z picks source/dest (dests adjacent).
// ---------------------------------------------------------------------------
__global__ __launch_bounds__(256) void wtrans2(const float* __restrict__ Wv,
                                               const float* __restrict__ Wo,
                                               short* __restrict__ WtBase)
{
    __shared__ short tile[64][80];
    const int n0 = blockIdx.x * 64, k0 = blockIdx.y * 64;
    const float* W = blockIdx.z ? Wo : Wv;
    short* Wt = WtBase + (size_t)blockIdx.z * Cc * Cc;
    const int tid = threadIdx.x;
#pragma unroll
    for (int i = 0; i < 4; ++i) {
        int e = i * 256 + tid;
        int k = e >> 4, n4 = (e & 15) * 4;
        float4 v = *(const float4*)&W[(size_t)(k0 + k) * Cc + n0 + n4];
        tile[k][n4]     = f2bf(v.x);
        tile[k][n4 + 1] = f2bf(v.y);
        tile[k][n4 + 2] = f2bf(v.z);
        tile[k][n4 + 3] = f2bf(v.w);
    }
    __syncthreads();
#pragma unroll
    for (int i = 0; i < 16; ++i) {
        int e = i * 256 + tid;
        int n = e >> 6, k = e & 63;
        Wt[(size_t)(n0 + n) * Cc + k0 + k] = tile[k][n];
    }
}

// ---------------------------------------------------------------------------
__global__ __launch_bounds__(256) void vtrans_bf(const short* __restrict__ v_bf,
                                                 short* __restrict__ v2t)
{
    __shared__ __attribute__((aligned(16))) short tile[64][80];
    const int t0 = blockIdx.x * 64, h = blockIdx.y, b = blockIdx.z;
    const int tid = threadIdx.x;
#pragma unroll
    for (int i = 0; i < 2; ++i) {
        int e = i * 256 + tid;
        int t = e >> 3, d8 = (e & 7) * 8;
        *(short8*)&tile[t][d8] =
            *(const short8*)&v_bf[(size_t)(b * Tc + t0 + t) * Cc + h * Dc + d8];
    }
    __syncthreads();
#pragma unroll
    for (int i = 0; i < 16; ++i) {
        int e = i * 256 + tid;
        int d = e >> 6, t = e & 63;
        v2t[((size_t)(b * Hc + h) * Dc + d) * Tc + t0 + t] = tile[t][d];
    }
}

// ---------------------------------------------------------------------------
// MFMA flash attention v3: fixed-max softmax (exact: scores tiny, softmax is
// shift-invariant), paired q-tiles, double-buffered global_load_lds staging,
// XOR swizzle, S^T formulation, 1 barrier per K-tile.
// ---------------------------------------------------------------------------
__global__ __launch_bounds__(256, 2) void moire_attn3(
    const short* __restrict__ q2, const short* __restrict__ k2,
    const short* __restrict__ v2t, const float* __restrict__ theta,
    short* __restrict__ att)
{
    __shared__ __attribute__((aligned(16))) short Ks[2][64 * 128];  // 32 KB
    __shared__ __attribute__((aligned(16))) short Vt[2][64 * 64];   // 16 KB
    __shared__ __attribute__((aligned(16))) short Ps[4][16 * 64];   //  8 KB

    const int tid = threadIdx.x;
    const int wave = tid >> 6, lane = tid & 63;
    const int quad = lane >> 4, c = lane & 15;
    const int p = blockIdx.x, h = blockIdx.y, b = blockIdx.z;
    const int qx[2] = {p, 31 - p};
    const int q0[2] = {p * 64, (31 - p) * 64};
    const float th = theta[h];

    const short* k2b = k2 + (size_t)(b * Hc + h) * Tc * 128;
    const short* v2b = v2t + (size_t)(b * Hc + h) * Dc * Tc;

    short8 qf[2][4];
#pragma unroll
    for (int tx = 0; tx < 2; ++tx) {
        const short* qp = q2 + ((size_t)(b * Hc + h) * Tc + q0[tx] + wave * 16 + c) * 128;
#pragma unroll
        for (int i = 0; i < 4; ++i)
            qf[tx][i] = *(const short8*)(qp + i * 32 + quad * 8);
    }

    // gate*log2e = csS*csT + snS*snT with (csS,snS) scaled by log2e at init;
    // the per-tile rotation is linear so the scale is preserved.
    const int t_l = wave * 16 + c;
    float csT[2], snT[2];
#pragma unroll
    for (int tx = 0; tx < 2; ++tx) {
        float at = th * 0.125f * (float)(q0[tx] + t_l);
        csT[tx] = __cosf(at);
        snT[tx] = __sinf(at);
    }
    float csS[4][4], snS[4][4];
#pragma unroll
    for (int mt = 0; mt < 4; ++mt)
#pragma unroll
        for (int reg = 0; reg < 4; ++reg) {
            float as = th * 0.125f * (float)(mt * 16 + quad * 4 + reg);
            csS[mt][reg] = __cosf(as) * L2E;
            snS[mt][reg] = __sinf(as) * L2E;
        }
    const float cD = __cosf(8.f * th), sD = __sinf(8.f * th);

    f32x4 oacc[2][4];
    float lsum[2] = {0.f, 0.f};
#pragma unroll
    for (int tx = 0; tx < 2; ++tx)
#pragma unroll
        for (int nt = 0; nt < 4; ++nt)
            oacc[tx][nt] = (f32x4){0.f, 0.f, 0.f, 0.f};

    auto stage = [&](int jts) {
        short* KsB = &Ks[jts & 1][0];
        short* VtB = &Vt[jts & 1][0];
        const int s0 = jts * 64;
#pragma unroll
        for (int i = 0; i < 4; ++i) {
            int ch = i * 256 + tid;
            int row = ch >> 4, j = ch & 15;
            const short* src = k2b + (size_t)(s0 + row) * 128 + ((j ^ (row & 15)) << 3);
            __builtin_amdgcn_global_load_lds(
                (const __attribute__((address_space(1))) void*)src,
                (__attribute__((address_space(3))) void*)(KsB + (i * 256 + wave * 64) * 8),
                16, 0, 0);
        }
#pragma unroll
        for (int i = 0; i < 2; ++i) {
            int ch = i * 256 + tid;
            int row = ch >> 3, j = ch & 7;
            const short* src = v2b + (size_t)row * Tc + s0 + ((j ^ (row & 7)) << 3);
            __builtin_amdgcn_global_load_lds(
                (const __attribute__((address_space(1))) void*)src,
                (__attribute__((address_space(3))) void*)(VtB + (i * 256 + wave * 64) * 8),
                16, 0, 0);
        }
    };

    stage(0);
    const int jtEnd = qx[1];
    for (int jt = 0; jt <= jtEnd; ++jt) {
        __syncthreads();
        if (jt < jtEnd) stage(jt + 1);

        const short* KsB = &Ks[jt & 1][0];
        const short* VtB = &Vt[jt & 1][0];

        const bool aAct = (jt <= qx[0]);
        f32x4 sA[4], sB[4];
#pragma unroll
        for (int mt = 0; mt < 4; ++mt) {
            sA[mt] = (f32x4){0.f, 0.f, 0.f, 0.f};
            sB[mt] = (f32x4){0.f, 0.f, 0.f, 0.f};
#pragma unroll
            for (int kk = 0; kk < 4; ++kk) {
                short8 kf = *(const short8*)&KsB[(mt * 16 + c) * 128 +
                                                 (((kk * 4 + quad) ^ c) << 3)];
                if (aAct) sA[mt] = __builtin_amdgcn_mfma_f32_16x16x32_bf16(
                                        kf, qf[0][kk], sA[mt], 0, 0, 0);
                sB[mt] = __builtin_amdgcn_mfma_f32_16x16x32_bf16(
                                        kf, qf[1][kk], sB[mt], 0, 0, 0);
            }
        }

#pragma unroll
        for (int tx = 0; tx < 2; ++tx) {
            if (tx == 0 && !aAct) continue;
            f32x4* sX = (tx == 0) ? sA : sB;
            const bool diag = (jt == qx[tx]);

            // p = exp2(s*gate*log2e - M*log2e); fixed shift M (exact softmax)
#pragma unroll
            for (int mt = 0; mt < 4; ++mt) {
                float pv[4];
#pragma unroll
                for (int reg = 0; reg < 4; ++reg) {
                    float g2 = csS[mt][reg] * csT[tx] + snS[mt][reg] * snT[tx];
                    float arg = fmaf(sX[mt][reg], g2, -SM_M * L2E);
                    if (diag && (mt * 16 + quad * 4 + reg) > t_l) arg = -1e30f;
                    pv[reg] = exp2f(arg);
                }
                lsum[tx] += (pv[0] + pv[1]) + (pv[2] + pv[3]);
                uint2 pk = {pack2bf(pv[0], pv[1]), pack2bf(pv[2], pv[3])};
                int slot = ((mt * 2 + (quad >> 1)) ^ (c & 7));
                *(uint2*)&Ps[wave][c * 64 + slot * 8 + (quad & 1) * 4] = pk;
            }

            short8 pf[2];
#pragma unroll
            for (int kk = 0; kk < 2; ++kk)
                pf[kk] = *(const short8*)&Ps[wave][c * 64 +
                             (((kk * 4 + quad) ^ (c & 7)) << 3)];
#pragma unroll
            for (int nt = 0; nt < 4; ++nt)
#pragma unroll
                for (int kk = 0; kk < 2; ++kk) {
                    short8 vf = *(const short8*)&VtB[(nt * 16 + c) * 64 +
                                 (((kk * 4 + quad) ^ (c & 7)) << 3)];
                    oacc[tx][nt] = __builtin_amdgcn_mfma_f32_16x16x32_bf16(
                        pf[kk], vf, oacc[tx][nt], 0, 0, 0);
                }
        }

        // advance s-angles by one tile (rotation by 8*th; preserves L2E scale)
#pragma unroll
        for (int mt = 0; mt < 4; ++mt)
#pragma unroll
            for (int reg = 0; reg < 4; ++reg) {
                float cs = csS[mt][reg], sn = snS[mt][reg];
                csS[mt][reg] = cs * cD - sn * sD;
                snS[mt][reg] = sn * cD + cs * sD;
            }
    }

    // epilogue: reduce l across quads, distribute 1/l to rows, write bf16
#pragma unroll
    for (int tx = 0; tx < 2; ++tx) {
        float l = lsum[tx];
        l += __shfl_xor(l, 16);
        l += __shfl_xor(l, 32);
        float il = 1.f / l;
        float ilr[4];
#pragma unroll
        for (int reg = 0; reg < 4; ++reg)
            ilr[reg] = __shfl(il, quad * 4 + reg);
#pragma unroll
        for (int reg = 0; reg < 4; ++reg) {
            int t_g = q0[tx] + wave * 16 + quad * 4 + reg;
#pragma unroll
            for (int nt = 0; nt < 4; ++nt)
                att[(size_t)(b * Tc + t_g) * Cc + h * Dc + nt * 16 + c] =
                    f2bf(oacc[tx][nt][reg] * ilr[reg]);
        }
    }
}

// ---------------------------------------------------------------------------
extern "C" void kernel_launch(void* const* d_in, const int* in_sizes, int n_in,
                              void* d_out, int out_size, void* d_ws, size_t ws_size,
                              hipStream_t stream)
{
    const float* x     = (const float*)d_in[0];
    const float* Wq    = (const float*)d_in[1];
    const float* Wk    = (const float*)d_in[2];
    const float* Wv    = (const float*)d_in[3];
    const float* Wo    = (const float*)d_in[4];
    const float* theta = (const float*)d_in[5];
    float* out = (float*)d_out;

    const int M = Bc * Tc;                 // 4096
    char* ws = (char*)d_ws;
    const size_t MB = 1 << 20;
    short* xb   = (short*)(ws);             // [0,8)   x bf16
    short* Bqk  = (short*)(ws + 8 * MB);    // [8,16)  interleaved [Wq'|Wk']^T bf16 (4096x1024)
    short* Wvt  = (short*)(ws + 16 * MB);   // [16,18)
    short* Wot  = (short*)(ws + 18 * MB);   // [18,20)
    short* v_bf = (short*)(ws + 20 * MB);   // [20,28)
    short* v2t  = (short*)(ws + 28 * MB);   // [28,36)
    short* attb = (short*)(ws + 36 * MB);   // [36,44)
    short* q2   = (short*)(ws + 44 * MB);   // [44,60) bf16 (B,H,T,128)
    short* k2   = (short*)d_out;            // 16 MB   bf16 (B,H,T,128) until final gemm

    xconv<<<(size_t)M * Cc / 1024, 256, 0, stream>>>(x, xb);
    wtrans_qk<<<dim3(2048 / 64, Cc / 64, 2), 256, 0, stream>>>(Wq, Wk, Bqk);
    wtrans2<<<dim3(Cc / 64, Cc / 64, 2), 256, 0, stream>>>(Wv, Wo, Wvt);

    // fused QK projection + moire transform (writes q2, k2 directly)
    gemm_bt_mfma<2><<<dim3(4096 / 128, M / 128), 256, 0, stream>>>(
        xb, Bqk, nullptr, q2, k2, M, 4096, Cc);
    gemm_bt_mfma<1><<<dim3(Cc / 128, M / 128), 256, 0, stream>>>(
        xb, Wvt, nullptr, v_bf, nullptr, M, Cc, Cc);

    vtrans_bf<<<dim3(Tc / 64, Hc, Bc), 256, 0, stream>>>(v_bf, v2t);

    moire_attn3<<<dim3(16, Hc, Bc), 256, 0, stream>>>(q2, k2, v2t, theta, attb);

    gemm_bt_mfma<0><<<dim3(Cc / 128, M / 128), 256, 0, stream>>>(
        attb, Wot, out, nullptr, nullptr, M, Cc, Cc);
}

// Round 6
// 308.656 us; speedup vs baseline: 1.8780x; 1.8780x over previous
//
#include <hip/hip_runtime.h>
#include <hip/hip_bf16.h>
#include <math.h>

// Problem constants
#define Bc 2
#define Tc 2048
#define Cc 1024
#define Hc 16
#define Dc 64
// SCALE = 1/8, GAMMA = 8

typedef __attribute__((ext_vector_type(8))) short short8;   // 8 bf16 (4 VGPRs)
typedef __attribute__((ext_vector_type(4))) float f32x4;    // MFMA C/D frag

#define L2E 1.44269504088896f
#define SM_M 20.0f   // fixed softmax shift; |scores| << 20 (std ~0.3)

__device__ __forceinline__ short f2bf(float x) {
    unsigned u = __float_as_uint(x);
    u += 0x7fff + ((u >> 16) & 1);      // RNE
    return (short)(u >> 16);
}
__device__ __forceinline__ unsigned pack2bf(float a, float b) {
    unsigned ua = __float_as_uint(a); ua += 0x7fff + ((ua >> 16) & 1);
    unsigned ub = __float_as_uint(b); ub += 0x7fff + ((ub >> 16) & 1);
    return (ua >> 16) | (ub & 0xffff0000u);
}
__device__ __forceinline__ float bf2f(short s) {
    return __uint_as_float(((unsigned)(unsigned short)s) << 16);
}

// ---------------------------------------------------------------------------
// bf16 MFMA GEMM (m97 recipe): C[M,N] = A[M,K] @ Bt[N,K]^T
// BF16_OUT selects f32 vs bf16 output. Plain contiguous epilogue only —
// R5 post-mortem: scattered 2-byte epilogue stores caused 60x HBM write
// amplification (1.94 GB for 32 MB payload). Keep stores lane-contiguous.
// ---------------------------------------------------------------------------
template <bool BF16_OUT>
__global__ __launch_bounds__(256) void gemm_bt_mfma(
    const short* __restrict__ A, const short* __restrict__ Bt,
    float* __restrict__ Cf, short* __restrict__ Cb, int M, int N, int K)
{
    __shared__ __attribute__((aligned(16))) short As[128 * 32];
    __shared__ __attribute__((aligned(16))) short Bs[128 * 32];

    const int tid = threadIdx.x;
    const int wave = tid >> 6, lane = tid & 63;
    const int quad = lane >> 4, c = lane & 15;
    const int wm = wave >> 1, wn = wave & 1;
    const int m0 = blockIdx.y * 128, n0 = blockIdx.x * 128;

    const int srow = lane >> 2;
    const int scol = (lane & 3) * 8;
    const short* Ag = A  + (size_t)(m0 + wave * 32 + srow) * K + scol;
    const short* Bg = Bt + (size_t)(n0 + wave * 32 + srow) * K + scol;
    short* AsW = As + (wave * 32) * 32;
    short* BsW = Bs + (wave * 32) * 32;

    f32x4 acc[4][4];
#pragma unroll
    for (int i = 0; i < 4; ++i)
#pragma unroll
        for (int j = 0; j < 4; ++j)
            acc[i][j] = (f32x4){0.f, 0.f, 0.f, 0.f};

    for (int k0 = 0; k0 < K; k0 += 32) {
        __syncthreads();
#pragma unroll
        for (int i = 0; i < 2; ++i) {
            __builtin_amdgcn_global_load_lds(
                (const __attribute__((address_space(1))) void*)(Ag + k0 + (size_t)i * 16 * K),
                (__attribute__((address_space(3))) void*)(AsW + i * 16 * 32), 16, 0, 0);
            __builtin_amdgcn_global_load_lds(
                (const __attribute__((address_space(1))) void*)(Bg + k0 + (size_t)i * 16 * K),
                (__attribute__((address_space(3))) void*)(BsW + i * 16 * 32), 16, 0, 0);
        }
        __syncthreads();

        short8 af[4], bf[4];
#pragma unroll
        for (int mt = 0; mt < 4; ++mt)
            af[mt] = *(const short8*)&As[(wm * 64 + mt * 16 + c) * 32 + quad * 8];
#pragma unroll
        for (int nt = 0; nt < 4; ++nt)
            bf[nt] = *(const short8*)&Bs[(wn * 64 + nt * 16 + c) * 32 + quad * 8];
#pragma unroll
        for (int mt = 0; mt < 4; ++mt)
#pragma unroll
            for (int nt = 0; nt < 4; ++nt)
                acc[mt][nt] = __builtin_amdgcn_mfma_f32_16x16x32_bf16(
                    af[mt], bf[nt], acc[mt][nt], 0, 0, 0);
    }

#pragma unroll
    for (int mt = 0; mt < 4; ++mt) {
#pragma unroll
        for (int reg = 0; reg < 4; ++reg) {
            size_t row = m0 + wm * 64 + mt * 16 + quad * 4 + reg;
#pragma unroll
            for (int nt = 0; nt < 4; ++nt) {
                size_t col = n0 + wn * 64 + nt * 16 + c;
                if (BF16_OUT) Cb[row * N + col] = f2bf(acc[mt][nt][reg]);
                else          Cf[row * N + col] = acc[mt][nt][reg];
            }
        }
    }
}

// ---------------------------------------------------------------------------
__global__ __launch_bounds__(256) void xconv(const float* __restrict__ x,
                                             short* __restrict__ xb)
{
    int idx = blockIdx.x * 256 + threadIdx.x;
    float4 v = *(const float4*)&x[(size_t)idx * 4];
    short4 o = {f2bf(v.x), f2bf(v.y), f2bf(v.z), f2bf(v.w)};
    *(short4*)&xb[(size_t)idx * 4] = o;
}

// ---------------------------------------------------------------------------
// Merged Wq|Wk transpose-convert -> Bt (4096 x 1024) bf16.
// z=0: Wq cols -> rows 0..2047.  z=1: Wk cols -> rows 2048..4095.
// ---------------------------------------------------------------------------
__global__ __launch_bounds__(256) void wtrans_qk(const float* __restrict__ Wq,
                                                 const float* __restrict__ Wk,
                                                 short* __restrict__ Bt)
{
    __shared__ short tile[64][80];
    const int n0 = blockIdx.x * 64, k0 = blockIdx.y * 64;
    const int half = blockIdx.z;
    const float* W = half ? Wk : Wq;
    const int tid = threadIdx.x;
#pragma unroll
    for (int i = 0; i < 4; ++i) {
        int e = i * 256 + tid;
        int k = e >> 4, n4 = (e & 15) * 4;
        float4 v = *(const float4*)&W[(size_t)(k0 + k) * 2048 + n0 + n4];
        tile[k][n4]     = f2bf(v.x);
        tile[k][n4 + 1] = f2bf(v.y);
        tile[k][n4 + 2] = f2bf(v.z);
        tile[k][n4 + 3] = f2bf(v.w);
    }
    __syncthreads();
#pragma unroll
    for (int i = 0; i < 16; ++i) {
        int e = i * 256 + tid;
        int n = e >> 6, k = e & 63;
        Bt[(size_t)(half * 2048 + n0 + n) * Cc + k0 + k] = tile[k][n];
    }
}

// ---------------------------------------------------------------------------
// Merged Wv|Wo transpose-convert: grid z picks source/dest (dests adjacent).
// ---------------------------------------------------------------------------
__global__ __launch_bounds__(256) void wtrans2(const float* __restrict__ Wv,
                                               const float* __restrict__ Wo,
                                               short* __restrict__ WtBase)
{
    __shared__ short tile[64][80];
    const int n0 = blockIdx.x * 64, k0 = blockIdx.y * 64;
    const float* W = blockIdx.z ? Wo : Wv;
    short* Wt = WtBase + (size_t)blockIdx.z * Cc * Cc;
    const int tid = threadIdx.x;
#pragma unroll
    for (int i = 0; i < 4; ++i) {
        int e = i * 256 + tid;
        int k = e >> 4, n4 = (e & 15) * 4;
        float4 v = *(const float4*)&W[(size_t)(k0 + k) * Cc + n0 + n4];
        tile[k][n4]     = f2bf(v.x);
        tile[k][n4 + 1] = f2bf(v.y);
        tile[k][n4 + 2] = f2bf(v.z);
        tile[k][n4 + 3] = f2bf(v.w);
    }
    __syncthreads();
#pragma unroll
    for (int i = 0; i < 16; ++i) {
        int e = i * 256 + tid;
        int n = e >> 6, k = e & 63;
        Wt[(size_t)(n0 + n) * Cc + k0 + k] = tile[k][n];
    }
}

// ---------------------------------------------------------------------------
// qkb (B,T,4096) bf16 [q amp 0..1023 | q ph 1024..2047 | k amp | k ph]
//   -> q2/k2 (B,H,T,128) bf16 = [sp*cos(ph) | sp*sin(ph)] * scale
// grid (16384, 2): y=0 -> q2 (scale 1/8), y=1 -> k2. Coalesced 2B lanes.
// ---------------------------------------------------------------------------
__global__ __launch_bounds__(256) void qk_transform(const short* __restrict__ qkb,
                                                    short* __restrict__ q2,
                                                    short* __restrict__ k2)
{
    int idx = blockIdx.x * 256 + threadIdx.x;   // B*H*T*64 = 2^22
    const int isK = blockIdx.y;
    int d = idx & 63;
    int t = (idx >> 6) & (Tc - 1);
    int h = (idx >> 17) & (Hc - 1);
    int b = idx >> 21;
    size_t base = (size_t)(b * Tc + t) * 4096 + isK * 2048 + h * Dc + d;
    float amp = bf2f(qkb[base]);
    float ph  = bf2f(qkb[base + Cc]);
    float sp = fmaxf(amp, 0.f) + log1pf(__expf(-fabsf(amp)));
    float sn, cs;
    __sincosf(ph, &sn, &cs);
    float scl = isK ? 1.f : 0.125f;
    short* dst = isK ? k2 : q2;
    size_t o = ((size_t)(b * Hc + h) * Tc + t) * 128 + d;
    dst[o]      = f2bf(sp * cs * scl);
    dst[o + 64] = f2bf(sp * sn * scl);
}

// ---------------------------------------------------------------------------
__global__ __launch_bounds__(256) void vtrans_bf(const short* __restrict__ v_bf,
                                                 short* __restrict__ v2t)
{
    __shared__ __attribute__((aligned(16))) short tile[64][80];
    const int t0 = blockIdx.x * 64, h = blockIdx.y, b = blockIdx.z;
    const int tid = threadIdx.x;
#pragma unroll
    for (int i = 0; i < 2; ++i) {
        int e = i * 256 + tid;
        int t = e >> 3, d8 = (e & 7) * 8;
        *(short8*)&tile[t][d8] =
            *(const short8*)&v_bf[(size_t)(b * Tc + t0 + t) * Cc + h * Dc + d8];
    }
    __syncthreads();
#pragma unroll
    for (int i = 0; i < 16; ++i) {
        int e = i * 256 + tid;
        int d = e >> 6, t = e & 63;
        v2t[((size_t)(b * Hc + h) * Dc + d) * Tc + t0 + t] = tile[t][d];
    }
}

// ---------------------------------------------------------------------------
// MFMA flash attention v3: fixed-max softmax (exact: scores tiny, softmax is
// shift-invariant), paired q-tiles, double-buffered global_load_lds staging,
// XOR swizzle, S^T formulation, 1 barrier per K-tile.
// ---------------------------------------------------------------------------
__global__ __launch_bounds__(256, 2) void moire_attn3(
    const short* __restrict__ q2, const short* __restrict__ k2,
    const short* __restrict__ v2t, const float* __restrict__ theta,
    short* __restrict__ att)
{
    __shared__ __attribute__((aligned(16))) short Ks[2][64 * 128];  // 32 KB
    __shared__ __attribute__((aligned(16))) short Vt[2][64 * 64];   // 16 KB
    __shared__ __attribute__((aligned(16))) short Ps[4][16 * 64];   //  8 KB

    const int tid = threadIdx.x;
    const int wave = tid >> 6, lane = tid & 63;
    const int quad = lane >> 4, c = lane & 15;
    const int p = blockIdx.x, h = blockIdx.y, b = blockIdx.z;
    const int qx[2] = {p, 31 - p};
    const int q0[2] = {p * 64, (31 - p) * 64};
    const float th = theta[h];

    const short* k2b = k2 + (size_t)(b * Hc + h) * Tc * 128;
    const short* v2b = v2t + (size_t)(b * Hc + h) * Dc * Tc;

    short8 qf[2][4];
#pragma unroll
    for (int tx = 0; tx < 2; ++tx) {
        const short* qp = q2 + ((size_t)(b * Hc + h) * Tc + q0[tx] + wave * 16 + c) * 128;
#pragma unroll
        for (int i = 0; i < 4; ++i)
            qf[tx][i] = *(const short8*)(qp + i * 32 + quad * 8);
    }

    // gate*log2e = csS*csT + snS*snT with (csS,snS) scaled by log2e at init;
    // the per-tile rotation is linear so the scale is preserved.
    const int t_l = wave * 16 + c;
    float csT[2], snT[2];
#pragma unroll
    for (int tx = 0; tx < 2; ++tx) {
        float at = th * 0.125f * (float)(q0[tx] + t_l);
        csT[tx] = __cosf(at);
        snT[tx] = __sinf(at);
    }
    float csS[4][4], snS[4][4];
#pragma unroll
    for (int mt = 0; mt < 4; ++mt)
#pragma unroll
        for (int reg = 0; reg < 4; ++reg) {
            float as = th * 0.125f * (float)(mt * 16 + quad * 4 + reg);
            csS[mt][reg] = __cosf(as) * L2E;
            snS[mt][reg] = __sinf(as) * L2E;
        }
    const float cD = __cosf(8.f * th), sD = __sinf(8.f * th);

    f32x4 oacc[2][4];
    float lsum[2] = {0.f, 0.f};
#pragma unroll
    for (int tx = 0; tx < 2; ++tx)
#pragma unroll
        for (int nt = 0; nt < 4; ++nt)
            oacc[tx][nt] = (f32x4){0.f, 0.f, 0.f, 0.f};

    auto stage = [&](int jts) {
        short* KsB = &Ks[jts & 1][0];
        short* VtB = &Vt[jts & 1][0];
        const int s0 = jts * 64;
#pragma unroll
        for (int i = 0; i < 4; ++i) {
            int ch = i * 256 + tid;
            int row = ch >> 4, j = ch & 15;
            const short* src = k2b + (size_t)(s0 + row) * 128 + ((j ^ (row & 15)) << 3);
            __builtin_amdgcn_global_load_lds(
                (const __attribute__((address_space(1))) void*)src,
                (__attribute__((address_space(3))) void*)(KsB + (i * 256 + wave * 64) * 8),
                16, 0, 0);
        }
#pragma unroll
        for (int i = 0; i < 2; ++i) {
            int ch = i * 256 + tid;
            int row = ch >> 3, j = ch & 7;
            const short* src = v2b + (size_t)row * Tc + s0 + ((j ^ (row & 7)) << 3);
            __builtin_amdgcn_global_load_lds(
                (const __attribute__((address_space(1))) void*)src,
                (__attribute__((address_space(3))) void*)(VtB + (i * 256 + wave * 64) * 8),
                16, 0, 0);
        }
    };

    stage(0);
    const int jtEnd = qx[1];
    for (int jt = 0; jt <= jtEnd; ++jt) {
        __syncthreads();
        if (jt < jtEnd) stage(jt + 1);

        const short* KsB = &Ks[jt & 1][0];
        const short* VtB = &Vt[jt & 1][0];

        const bool aAct = (jt <= qx[0]);
        f32x4 sA[4], sB[4];
#pragma unroll
        for (int mt = 0; mt < 4; ++mt) {
            sA[mt] = (f32x4){0.f, 0.f, 0.f, 0.f};
            sB[mt] = (f32x4){0.f, 0.f, 0.f, 0.f};
#pragma unroll
            for (int kk = 0; kk < 4; ++kk) {
                short8 kf = *(const short8*)&KsB[(mt * 16 + c) * 128 +
                                                 (((kk * 4 + quad) ^ c) << 3)];
                if (aAct) sA[mt] = __builtin_amdgcn_mfma_f32_16x16x32_bf16(
                                        kf, qf[0][kk], sA[mt], 0, 0, 0);
                sB[mt] = __builtin_amdgcn_mfma_f32_16x16x32_bf16(
                                        kf, qf[1][kk], sB[mt], 0, 0, 0);
            }
        }

#pragma unroll
        for (int tx = 0; tx < 2; ++tx) {
            if (tx == 0 && !aAct) continue;
            f32x4* sX = (tx == 0) ? sA : sB;
            const bool diag = (jt == qx[tx]);

            // p = exp2(s*gate*log2e - M*log2e); fixed shift M (exact softmax)
#pragma unroll
            for (int mt = 0; mt < 4; ++mt) {
                float pv[4];
#pragma unroll
                for (int reg = 0; reg < 4; ++reg) {
                    float g2 = csS[mt][reg] * csT[tx] + snS[mt][reg] * snT[tx];
                    float arg = fmaf(sX[mt][reg], g2, -SM_M * L2E);
                    if (diag && (mt * 16 + quad * 4 + reg) > t_l) arg = -1e30f;
                    pv[reg] = exp2f(arg);
                }
                lsum[tx] += (pv[0] + pv[1]) + (pv[2] + pv[3]);
                uint2 pk = {pack2bf(pv[0], pv[1]), pack2bf(pv[2], pv[3])};
                int slot = ((mt * 2 + (quad >> 1)) ^ (c & 7));
                *(uint2*)&Ps[wave][c * 64 + slot * 8 + (quad & 1) * 4] = pk;
            }

            short8 pf[2];
#pragma unroll
            for (int kk = 0; kk < 2; ++kk)
                pf[kk] = *(const short8*)&Ps[wave][c * 64 +
                             (((kk * 4 + quad) ^ (c & 7)) << 3)];
#pragma unroll
            for (int nt = 0; nt < 4; ++nt)
#pragma unroll
                for (int kk = 0; kk < 2; ++kk) {
                    short8 vf = *(const short8*)&VtB[(nt * 16 + c) * 64 +
                                 (((kk * 4 + quad) ^ (c & 7)) << 3)];
                    oacc[tx][nt] = __builtin_amdgcn_mfma_f32_16x16x32_bf16(
                        pf[kk], vf, oacc[tx][nt], 0, 0, 0);
                }
        }

        // advance s-angles by one tile (rotation by 8*th; preserves L2E scale)
#pragma unroll
        for (int mt = 0; mt < 4; ++mt)
#pragma unroll
            for (int reg = 0; reg < 4; ++reg) {
                float cs = csS[mt][reg], sn = snS[mt][reg];
                csS[mt][reg] = cs * cD - sn * sD;
                snS[mt][reg] = sn * cD + cs * sD;
            }
    }

    // epilogue: reduce l across quads, distribute 1/l to rows, write bf16
#pragma unroll
    for (int tx = 0; tx < 2; ++tx) {
        float l = lsum[tx];
        l += __shfl_xor(l, 16);
        l += __shfl_xor(l, 32);
        float il = 1.f / l;
        float ilr[4];
#pragma unroll
        for (int reg = 0; reg < 4; ++reg)
            ilr[reg] = __shfl(il, quad * 4 + reg);
#pragma unroll
        for (int reg = 0; reg < 4; ++reg) {
            int t_g = q0[tx] + wave * 16 + quad * 4 + reg;
#pragma unroll
            for (int nt = 0; nt < 4; ++nt)
                att[(size_t)(b * Tc + t_g) * Cc + h * Dc + nt * 16 + c] =
                    f2bf(oacc[tx][nt][reg] * ilr[reg]);
        }
    }
}

// ---------------------------------------------------------------------------
extern "C" void kernel_launch(void* const* d_in, const int* in_sizes, int n_in,
                              void* d_out, int out_size, void* d_ws, size_t ws_size,
                              hipStream_t stream)
{
    const float* x     = (const float*)d_in[0];
    const float* Wq    = (const float*)d_in[1];
    const float* Wk    = (const float*)d_in[2];
    const float* Wv    = (const float*)d_in[3];
    const float* Wo    = (const float*)d_in[4];
    const float* theta = (const float*)d_in[5];
    float* out = (float*)d_out;

    const int M = Bc * Tc;                 // 4096
    char* ws = (char*)d_ws;
    const size_t MB = 1 << 20;
    short* xb   = (short*)(ws);             // [0,8)   x bf16
    short* Bqk  = (short*)(ws + 8 * MB);    // [8,16)  [Wq^T; Wk^T] bf16 (4096x1024)
    short* Wvt  = (short*)(ws + 16 * MB);   // [16,18)
    short* Wot  = (short*)(ws + 18 * MB);   // [18,20)
    short* v_bf = (short*)(ws + 20 * MB);   // [20,28)
    short* v2t  = (short*)(ws + 28 * MB);   // [28,36)
    short* attb = (short*)(ws + 36 * MB);   // [36,44)
    short* q2   = (short*)(ws + 44 * MB);   // [44,60) bf16 (B,H,T,128)
    short* qkb  = (short*)(ws + 60 * MB);   // [60,92) bf16 (4096 x 4096) raw q|k
    short* k2   = (short*)d_out;            // 16 MB   bf16 (B,H,T,128) until final gemm

    xconv<<<(size_t)M * Cc / 1024, 256, 0, stream>>>(x, xb);
    wtrans_qk<<<dim3(2048 / 64, Cc / 64, 2), 256, 0, stream>>>(Wq, Wk, Bqk);
    wtrans2<<<dim3(Cc / 64, Cc / 64, 2), 256, 0, stream>>>(Wv, Wo, Wvt);

    // QK projection (bf16 out, coalesced) + V projection
    gemm_bt_mfma<true><<<dim3(4096 / 128, M / 128), 256, 0, stream>>>(
        xb, Bqk, nullptr, qkb, M, 4096, Cc);
    gemm_bt_mfma<true><<<dim3(Cc / 128, M / 128), 256, 0, stream>>>(
        xb, Wvt, nullptr, v_bf, M, Cc, Cc);

    // moire transform (q and k in one dispatch) + V head-transpose
    qk_transform<<<dim3((Bc * Hc * Tc * Dc) / 256, 2), 256, 0, stream>>>(qkb, q2, k2);
    vtrans_bf<<<dim3(Tc / 64, Hc, Bc), 256, 0, stream>>>(v_bf, v2t);

    moire_attn3<<<dim3(16, Hc, Bc), 256, 0, stream>>>(q2, k2, v2t, theta, attb);

    gemm_bt_mfma<false><<<dim3(Cc / 128, M / 128), 256, 0, stream>>>(
        attb, Wot, out, nullptr, M, Cc, Cc);
}

// Round 7
// 305.646 us; speedup vs baseline: 1.8965x; 1.0098x over previous
//
#include <hip/hip_runtime.h>
#include <hip/hip_bf16.h>
#include <math.h>

// Problem constants
#define Bc 2
#define Tc 2048
#define Cc 1024
#define Hc 16
#define Dc 64
// SCALE = 1/8, GAMMA = 8

typedef __attribute__((ext_vector_type(8))) short short8;   // 8 bf16 (4 VGPRs)
typedef __attribute__((ext_vector_type(4))) float f32x4;    // MFMA C/D frag

#define L2E 1.44269504088896f
#define SM_M 20.0f   // fixed softmax shift; |scores| << 20 (std ~0.3)

__device__ __forceinline__ short f2bf(float x) {
    unsigned u = __float_as_uint(x);
    u += 0x7fff + ((u >> 16) & 1);      // RNE
    return (short)(u >> 16);
}
// pack two non-negative floats to bf16 pair (round-half-up) in 3 VALU ops
__device__ __forceinline__ unsigned pack2bf_fast(float a, float b) {
    unsigned ua = __float_as_uint(a) + 0x8000u;
    unsigned ub = __float_as_uint(b) + 0x8000u;
    return __builtin_amdgcn_perm(ub, ua, 0x07060302);  // (ua>>16)|(ub&0xffff0000)
}
__device__ __forceinline__ float bf2f(short s) {
    return __uint_as_float(((unsigned)(unsigned short)s) << 16);
}

// ---------------------------------------------------------------------------
// bf16 MFMA GEMM (m97 recipe): C[M,N] = A[M,K] @ Bt[N,K]^T
// R5 post-mortem: keep epilogue stores lane-contiguous (scattered 2B stores
// caused 60x HBM write amplification).
// ---------------------------------------------------------------------------
template <bool BF16_OUT>
__global__ __launch_bounds__(256) void gemm_bt_mfma(
    const short* __restrict__ A, const short* __restrict__ Bt,
    float* __restrict__ Cf, short* __restrict__ Cb, int M, int N, int K)
{
    __shared__ __attribute__((aligned(16))) short As[128 * 32];
    __shared__ __attribute__((aligned(16))) short Bs[128 * 32];

    const int tid = threadIdx.x;
    const int wave = tid >> 6, lane = tid & 63;
    const int quad = lane >> 4, c = lane & 15;
    const int wm = wave >> 1, wn = wave & 1;
    const int m0 = blockIdx.y * 128, n0 = blockIdx.x * 128;

    const int srow = lane >> 2;
    const int scol = (lane & 3) * 8;
    const short* Ag = A  + (size_t)(m0 + wave * 32 + srow) * K + scol;
    const short* Bg = Bt + (size_t)(n0 + wave * 32 + srow) * K + scol;
    short* AsW = As + (wave * 32) * 32;
    short* BsW = Bs + (wave * 32) * 32;

    f32x4 acc[4][4];
#pragma unroll
    for (int i = 0; i < 4; ++i)
#pragma unroll
        for (int j = 0; j < 4; ++j)
            acc[i][j] = (f32x4){0.f, 0.f, 0.f, 0.f};

    for (int k0 = 0; k0 < K; k0 += 32) {
        __syncthreads();
#pragma unroll
        for (int i = 0; i < 2; ++i) {
            __builtin_amdgcn_global_load_lds(
                (const __attribute__((address_space(1))) void*)(Ag + k0 + (size_t)i * 16 * K),
                (__attribute__((address_space(3))) void*)(AsW + i * 16 * 32), 16, 0, 0);
            __builtin_amdgcn_global_load_lds(
                (const __attribute__((address_space(1))) void*)(Bg + k0 + (size_t)i * 16 * K),
                (__attribute__((address_space(3))) void*)(BsW + i * 16 * 32), 16, 0, 0);
        }
        __syncthreads();

        short8 af[4], bf[4];
#pragma unroll
        for (int mt = 0; mt < 4; ++mt)
            af[mt] = *(const short8*)&As[(wm * 64 + mt * 16 + c) * 32 + quad * 8];
#pragma unroll
        for (int nt = 0; nt < 4; ++nt)
            bf[nt] = *(const short8*)&Bs[(wn * 64 + nt * 16 + c) * 32 + quad * 8];
#pragma unroll
        for (int mt = 0; mt < 4; ++mt)
#pragma unroll
            for (int nt = 0; nt < 4; ++nt)
                acc[mt][nt] = __builtin_amdgcn_mfma_f32_16x16x32_bf16(
                    af[mt], bf[nt], acc[mt][nt], 0, 0, 0);
    }

#pragma unroll
    for (int mt = 0; mt < 4; ++mt) {
#pragma unroll
        for (int reg = 0; reg < 4; ++reg) {
            size_t row = m0 + wm * 64 + mt * 16 + quad * 4 + reg;
#pragma unroll
            for (int nt = 0; nt < 4; ++nt) {
                size_t col = n0 + wn * 64 + nt * 16 + c;
                if (BF16_OUT) Cb[row * N + col] = f2bf(acc[mt][nt][reg]);
                else          Cf[row * N + col] = acc[mt][nt][reg];
            }
        }
    }
}

// ---------------------------------------------------------------------------
__global__ __launch_bounds__(256) void xconv(const float* __restrict__ x,
                                             short* __restrict__ xb)
{
    int idx = blockIdx.x * 256 + threadIdx.x;
    float4 v = *(const float4*)&x[(size_t)idx * 4];
    short4 o = {f2bf(v.x), f2bf(v.y), f2bf(v.z), f2bf(v.w)};
    *(short4*)&xb[(size_t)idx * 4] = o;
}

// ---------------------------------------------------------------------------
// Merged Wq|Wk transpose-convert -> Bt (4096 x 1024) bf16.
// ---------------------------------------------------------------------------
__global__ __launch_bounds__(256) void wtrans_qk(const float* __restrict__ Wq,
                                                 const float* __restrict__ Wk,
                                                 short* __restrict__ Bt)
{
    __shared__ short tile[64][80];
    const int n0 = blockIdx.x * 64, k0 = blockIdx.y * 64;
    const int half = blockIdx.z;
    const float* W = half ? Wk : Wq;
    const int tid = threadIdx.x;
#pragma unroll
    for (int i = 0; i < 4; ++i) {
        int e = i * 256 + tid;
        int k = e >> 4, n4 = (e & 15) * 4;
        float4 v = *(const float4*)&W[(size_t)(k0 + k) * 2048 + n0 + n4];
        tile[k][n4]     = f2bf(v.x);
        tile[k][n4 + 1] = f2bf(v.y);
        tile[k][n4 + 2] = f2bf(v.z);
        tile[k][n4 + 3] = f2bf(v.w);
    }
    __syncthreads();
#pragma unroll
    for (int i = 0; i < 16; ++i) {
        int e = i * 256 + tid;
        int n = e >> 6, k = e & 63;
        Bt[(size_t)(half * 2048 + n0 + n) * Cc + k0 + k] = tile[k][n];
    }
}

// ---------------------------------------------------------------------------
__global__ __launch_bounds__(256) void wtrans2(const float* __restrict__ Wv,
                                               const float* __restrict__ Wo,
                                               short* __restrict__ WtBase)
{
    __shared__ short tile[64][80];
    const int n0 = blockIdx.x * 64, k0 = blockIdx.y * 64;
    const float* W = blockIdx.z ? Wo : Wv;
    short* Wt = WtBase + (size_t)blockIdx.z * Cc * Cc;
    const int tid = threadIdx.x;
#pragma unroll
    for (int i = 0; i < 4; ++i) {
        int e = i * 256 + tid;
        int k = e >> 4, n4 = (e & 15) * 4;
        float4 v = *(const float4*)&W[(size_t)(k0 + k) * Cc + n0 + n4];
        tile[k][n4]     = f2bf(v.x);
        tile[k][n4 + 1] = f2bf(v.y);
        tile[k][n4 + 2] = f2bf(v.z);
        tile[k][n4 + 3] = f2bf(v.w);
    }
    __syncthreads();
#pragma unroll
    for (int i = 0; i < 16; ++i) {
        int e = i * 256 + tid;
        int n = e >> 6, k = e & 63;
        Wt[(size_t)(n0 + n) * Cc + k0 + k] = tile[k][n];
    }
}

// ---------------------------------------------------------------------------
// qkb (B,T,4096) bf16 -> q2/k2 (B,H,T,128) bf16 moire transform
// ---------------------------------------------------------------------------
__global__ __launch_bounds__(256) void qk_transform(const short* __restrict__ qkb,
                                                    short* __restrict__ q2,
                                                    short* __restrict__ k2)
{
    int idx = blockIdx.x * 256 + threadIdx.x;   // B*H*T*64 = 2^22
    const int isK = blockIdx.y;
    int d = idx & 63;
    int t = (idx >> 6) & (Tc - 1);
    int h = (idx >> 17) & (Hc - 1);
    int b = idx >> 21;
    size_t base = (size_t)(b * Tc + t) * 4096 + isK * 2048 + h * Dc + d;
    float amp = bf2f(qkb[base]);
    float ph  = bf2f(qkb[base + Cc]);
    float sp = fmaxf(amp, 0.f) + log1pf(__expf(-fabsf(amp)));
    float sn, cs;
    __sincosf(ph, &sn, &cs);
    float scl = isK ? 1.f : 0.125f;
    short* dst = isK ? k2 : q2;
    size_t o = ((size_t)(b * Hc + h) * Tc + t) * 128 + d;
    dst[o]      = f2bf(sp * cs * scl);
    dst[o + 64] = f2bf(sp * sn * scl);
}

// ---------------------------------------------------------------------------
__global__ __launch_bounds__(256) void vtrans_bf(const short* __restrict__ v_bf,
                                                 short* __restrict__ v2t)
{
    __shared__ __attribute__((aligned(16))) short tile[64][80];
    const int t0 = blockIdx.x * 64, h = blockIdx.y, b = blockIdx.z;
    const int tid = threadIdx.x;
#pragma unroll
    for (int i = 0; i < 2; ++i) {
        int e = i * 256 + tid;
        int t = e >> 3, d8 = (e & 7) * 8;
        *(short8*)&tile[t][d8] =
            *(const short8*)&v_bf[(size_t)(b * Tc + t0 + t) * Cc + h * Dc + d8];
    }
    __syncthreads();
#pragma unroll
    for (int i = 0; i < 16; ++i) {
        int e = i * 256 + tid;
        int d = e >> 6, t = e & 63;
        v2t[((size_t)(b * Hc + h) * Dc + d) * Tc + t0 + t] = tile[t][d];
    }
}

// ---------------------------------------------------------------------------
// MFMA flash attention v4: 512 threads / 8 waves. Waves 0-3 own q-tile p,
// waves 4-7 own q-tile 31-p (per-wave work halves; waves/SIMD 2->4 at
// 2 blocks/CU to hide the per-iteration latency chain — R6 post-mortem
// showed the kernel latency-bound, not VALU-bound). Fixed-max softmax,
// double-buffered global_load_lds staging, XOR swizzle, S^T formulation,
// 1 barrier per K-tile. LDS 64 KB.
// ---------------------------------------------------------------------------
__global__ __launch_bounds__(512, 4) void moire_attn4(
    const short* __restrict__ q2, const short* __restrict__ k2,
    const short* __restrict__ v2t, const float* __restrict__ theta,
    short* __restrict__ att)
{
    __shared__ __attribute__((aligned(16))) short Ks[2][64 * 128];  // 32 KB
    __shared__ __attribute__((aligned(16))) short Vt[2][64 * 64];   // 16 KB
    __shared__ __attribute__((aligned(16))) short Ps[8][16 * 64];   // 16 KB

    const int tid = threadIdx.x;
    const int wave = tid >> 6, lane = tid & 63;
    const int quad = lane >> 4, c = lane & 15;
    const int tx = wave >> 2, wq = wave & 3;
    const int p = blockIdx.x, h = blockIdx.y, b = blockIdx.z;
    const int qx = tx ? (31 - p) : p;    // this wave's q-tile
    const int q0 = qx * 64;
    const float th = theta[h];

    const short* k2b = k2 + (size_t)(b * Hc + h) * Tc * 128;
    const short* v2b = v2t + (size_t)(b * Hc + h) * Dc * Tc;

    // Q B-frags (n = t): row q0 + wq*16 + c, 4 K-chunks of 32
    short8 qf[4];
    const short* qp = q2 + ((size_t)(b * Hc + h) * Tc + q0 + wq * 16 + c) * 128;
#pragma unroll
    for (int i = 0; i < 4; ++i)
        qf[i] = *(const short8*)(qp + i * 32 + quad * 8);

    // theta gate: gate*log2e = csS*csT + snS*snT; (csS,snS) carry the L2E
    // scale; per-tile rotation is linear so the scale is preserved.
    const int t_l = wq * 16 + c;
    float at = th * 0.125f * (float)(q0 + t_l);
    float csT = __cosf(at), snT = __sinf(at);
    float csS[4][4], snS[4][4];
#pragma unroll
    for (int mt = 0; mt < 4; ++mt)
#pragma unroll
        for (int reg = 0; reg < 4; ++reg) {
            float as = th * 0.125f * (float)(mt * 16 + quad * 4 + reg);
            csS[mt][reg] = __cosf(as) * L2E;
            snS[mt][reg] = __sinf(as) * L2E;
        }
    const float cD = __cosf(8.f * th), sD = __sinf(8.f * th);

    f32x4 oacc[4];
    float lsum = 0.f;
#pragma unroll
    for (int nt = 0; nt < 4; ++nt)
        oacc[nt] = (f32x4){0.f, 0.f, 0.f, 0.f};

    auto stage = [&](int jts) {
        short* KsB = &Ks[jts & 1][0];
        short* VtB = &Vt[jts & 1][0];
        const int s0 = jts * 64;
#pragma unroll
        for (int i = 0; i < 2; ++i) {          // Ks: 1024 16B chunks
            int ch = i * 512 + tid;
            int row = ch >> 4, j = ch & 15;
            const short* src = k2b + (size_t)(s0 + row) * 128 + ((j ^ (row & 15)) << 3);
            __builtin_amdgcn_global_load_lds(
                (const __attribute__((address_space(1))) void*)src,
                (__attribute__((address_space(3))) void*)(KsB + (i * 512 + wave * 64) * 8),
                16, 0, 0);
        }
        {                                       // Vt: 512 16B chunks
            int ch = tid;
            int row = ch >> 3, j = ch & 7;
            const short* src = v2b + (size_t)row * Tc + s0 + ((j ^ (row & 7)) << 3);
            __builtin_amdgcn_global_load_lds(
                (const __attribute__((address_space(1))) void*)src,
                (__attribute__((address_space(3))) void*)(VtB + (wave * 64) * 8),
                16, 0, 0);
        }
    };

    stage(0);
    const int jtEnd = 31 - p;                   // tx=1 end >= tx=0 end
    for (int jt = 0; jt <= jtEnd; ++jt) {
        __syncthreads();
        if (jt < jtEnd) stage(jt + 1);

        if (jt <= qx) {
            const short* KsB = &Ks[jt & 1][0];
            const short* VtB = &Vt[jt & 1][0];
            const bool diag = (jt == qx);

            // S^T = K Q^T : kf A-operand (m=s), qf B-operand (n=t)
            f32x4 s_acc[4];
#pragma unroll
            for (int mt = 0; mt < 4; ++mt) {
                f32x4 a = {0.f, 0.f, 0.f, 0.f};
#pragma unroll
                for (int kk = 0; kk < 4; ++kk) {
                    short8 kf = *(const short8*)&KsB[(mt * 16 + c) * 128 +
                                                     (((kk * 4 + quad) ^ c) << 3)];
                    a = __builtin_amdgcn_mfma_f32_16x16x32_bf16(kf, qf[kk], a, 0, 0, 0);
                }
                s_acc[mt] = a;
            }

            // p = exp2(s*gate*log2e - M*log2e); fixed shift M (exact softmax)
#pragma unroll
            for (int mt = 0; mt < 4; ++mt) {
                float pv[4];
#pragma unroll
                for (int reg = 0; reg < 4; ++reg) {
                    float g2 = csS[mt][reg] * csT + snS[mt][reg] * snT;
                    float arg = fmaf(s_acc[mt][reg], g2, -SM_M * L2E);
                    if (diag && (mt * 16 + quad * 4 + reg) > t_l) arg = -1e30f;
                    pv[reg] = exp2f(arg);
                }
                lsum += (pv[0] + pv[1]) + (pv[2] + pv[3]);
                uint2 pk = {pack2bf_fast(pv[0], pv[1]), pack2bf_fast(pv[2], pv[3])};
                int slot = ((mt * 2 + (quad >> 1)) ^ (c & 7));
                *(uint2*)&Ps[wave][c * 64 + slot * 8 + (quad & 1) * 4] = pk;
            }

            // O += P V : pf A-operand (m=t) from own wave's Ps row c
            short8 pf[2];
#pragma unroll
            for (int kk = 0; kk < 2; ++kk)
                pf[kk] = *(const short8*)&Ps[wave][c * 64 +
                             (((kk * 4 + quad) ^ (c & 7)) << 3)];
#pragma unroll
            for (int nt = 0; nt < 4; ++nt)
#pragma unroll
                for (int kk = 0; kk < 2; ++kk) {
                    short8 vf = *(const short8*)&VtB[(nt * 16 + c) * 64 +
                                 (((kk * 4 + quad) ^ (c & 7)) << 3)];
                    oacc[nt] = __builtin_amdgcn_mfma_f32_16x16x32_bf16(
                        pf[kk], vf, oacc[nt], 0, 0, 0);
                }

            // advance s-angles by one tile (only while active)
#pragma unroll
            for (int mt = 0; mt < 4; ++mt)
#pragma unroll
                for (int reg = 0; reg < 4; ++reg) {
                    float cs = csS[mt][reg], sn = snS[mt][reg];
                    csS[mt][reg] = cs * cD - sn * sD;
                    snS[mt][reg] = sn * cD + cs * sD;
                }
        }
    }

    // epilogue: reduce l across quads, distribute 1/l to rows, write bf16
    float l = lsum;
    l += __shfl_xor(l, 16);
    l += __shfl_xor(l, 32);
    float il = 1.f / l;
    float ilr[4];
#pragma unroll
    for (int reg = 0; reg < 4; ++reg)
        ilr[reg] = __shfl(il, quad * 4 + reg);
#pragma unroll
    for (int reg = 0; reg < 4; ++reg) {
        int t_g = q0 + wq * 16 + quad * 4 + reg;
#pragma unroll
        for (int nt = 0; nt < 4; ++nt)
            att[(size_t)(b * Tc + t_g) * Cc + h * Dc + nt * 16 + c] =
                f2bf(oacc[nt][reg] * ilr[reg]);
    }
}

// ---------------------------------------------------------------------------
extern "C" void kernel_launch(void* const* d_in, const int* in_sizes, int n_in,
                              void* d_out, int out_size, void* d_ws, size_t ws_size,
                              hipStream_t stream)
{
    const float* x     = (const float*)d_in[0];
    const float* Wq    = (const float*)d_in[1];
    const float* Wk    = (const float*)d_in[2];
    const float* Wv    = (const float*)d_in[3];
    const float* Wo    = (const float*)d_in[4];
    const float* theta = (const float*)d_in[5];
    float* out = (float*)d_out;

    const int M = Bc * Tc;                 // 4096
    char* ws = (char*)d_ws;
    const size_t MB = 1 << 20;
    short* xb   = (short*)(ws);             // [0,8)   x bf16
    short* Bqk  = (short*)(ws + 8 * MB);    // [8,16)  [Wq^T; Wk^T] bf16 (4096x1024)
    short* Wvt  = (short*)(ws + 16 * MB);   // [16,18)
    short* Wot  = (short*)(ws + 18 * MB);   // [18,20)
    short* v_bf = (short*)(ws + 20 * MB);   // [20,28)
    short* v2t  = (short*)(ws + 28 * MB);   // [28,36)
    short* attb = (short*)(ws + 36 * MB);   // [36,44)
    short* q2   = (short*)(ws + 44 * MB);   // [44,60) bf16 (B,H,T,128)
    short* qkb  = (short*)(ws + 60 * MB);   // [60,92) bf16 (4096 x 4096) raw q|k
    short* k2   = (short*)d_out;            // 16 MB   bf16 (B,H,T,128) until final gemm

    xconv<<<(size_t)M * Cc / 1024, 256, 0, stream>>>(x, xb);
    wtrans_qk<<<dim3(2048 / 64, Cc / 64, 2), 256, 0, stream>>>(Wq, Wk, Bqk);
    wtrans2<<<dim3(Cc / 64, Cc / 64, 2), 256, 0, stream>>>(Wv, Wo, Wvt);

    // QK projection (bf16 out, coalesced) + V projection
    gemm_bt_mfma<true><<<dim3(4096 / 128, M / 128), 256, 0, stream>>>(
        xb, Bqk, nullptr, qkb, M, 4096, Cc);
    gemm_bt_mfma<true><<<dim3(Cc / 128, M / 128), 256, 0, stream>>>(
        xb, Wvt, nullptr, v_bf, M, Cc, Cc);

    // moire transform (q and k in one dispatch) + V head-transpose
    qk_transform<<<dim3((Bc * Hc * Tc * Dc) / 256, 2), 256, 0, stream>>>(qkb, q2, k2);
    vtrans_bf<<<dim3(Tc / 64, Hc, Bc), 256, 0, stream>>>(v_bf, v2t);

    moire_attn4<<<dim3(16, Hc, Bc), 512, 0, stream>>>(q2, k2, v2t, theta, attb);

    gemm_bt_mfma<false><<<dim3(Cc / 128, M / 128), 256, 0, stream>>>(
        attb, Wot, out, nullptr, M, Cc, Cc);
}

// Round 8
// 287.888 us; speedup vs baseline: 2.0135x; 1.0617x over previous
//
#include <hip/hip_runtime.h>
#include <hip/hip_bf16.h>
#include <math.h>

// Problem constants
#define Bc 2
#define Tc 2048
#define Cc 1024
#define Hc 16
#define Dc 64
// SCALE = 1/8, GAMMA = 8

typedef __attribute__((ext_vector_type(8))) short short8;   // 8 bf16 (4 VGPRs)
typedef __attribute__((ext_vector_type(4))) float f32x4;    // MFMA C/D frag

#define L2E 1.44269504088896f
#define SM_M 20.0f   // fixed softmax shift; |scores| << 20 (std ~0.3)

__device__ __forceinline__ short f2bf(float x) {
    unsigned u = __float_as_uint(x);
    u += 0x7fff + ((u >> 16) & 1);      // RNE
    return (short)(u >> 16);
}
// pack two non-negative floats to bf16 pair (round-half-up) in 3 VALU ops
__device__ __forceinline__ unsigned pack2bf_fast(float a, float b) {
    unsigned ua = __float_as_uint(a) + 0x8000u;
    unsigned ub = __float_as_uint(b) + 0x8000u;
    return __builtin_amdgcn_perm(ub, ua, 0x07060302);  // (ua>>16)|(ub&0xffff0000)
}
__device__ __forceinline__ float softplusf(float a) {
    return fmaxf(a, 0.f) + log1pf(__expf(-fabsf(a)));
}

// ---------------------------------------------------------------------------
// bf16 MFMA GEMM (m97 recipe): C[M,N] = A[M,K] @ Bt[N,K]^T
// EPI 0: f32 out. EPI 1: bf16 out. EPI 2: fused moire-QK epilogue.
// EPI 2 requires the Bqk row layout from wtrans_qk below: each wave's 64
// cols = [amp(h, d0..d0+31) | phase(h, d0..d0+31)], so n-tiles 0,1 are amp
// and 2,3 the matching phase IN THE SAME LANE -> no shuffle, and q2/k2
// stores are 16-lane-contiguous 32B runs (R5 post-mortem: scattered 2B
// epilogue stores caused 60x HBM write amplification; this layout avoids it).
// ---------------------------------------------------------------------------
template <int EPI>
__global__ __launch_bounds__(256) void gemm_bt_mfma(
    const short* __restrict__ A, const short* __restrict__ Bt,
    float* __restrict__ Cf, short* __restrict__ Cb, short* __restrict__ Cb2,
    int M, int N, int K)
{
    __shared__ __attribute__((aligned(16))) short As[128 * 32];
    __shared__ __attribute__((aligned(16))) short Bs[128 * 32];

    const int tid = threadIdx.x;
    const int wave = tid >> 6, lane = tid & 63;
    const int quad = lane >> 4, c = lane & 15;
    const int wm = wave >> 1, wn = wave & 1;
    const int m0 = blockIdx.y * 128, n0 = blockIdx.x * 128;

    const int srow = lane >> 2;
    const int scol = (lane & 3) * 8;
    const short* Ag = A  + (size_t)(m0 + wave * 32 + srow) * K + scol;
    const short* Bg = Bt + (size_t)(n0 + wave * 32 + srow) * K + scol;
    short* AsW = As + (wave * 32) * 32;
    short* BsW = Bs + (wave * 32) * 32;

    f32x4 acc[4][4];
#pragma unroll
    for (int i = 0; i < 4; ++i)
#pragma unroll
        for (int j = 0; j < 4; ++j)
            acc[i][j] = (f32x4){0.f, 0.f, 0.f, 0.f};

    for (int k0 = 0; k0 < K; k0 += 32) {
        __syncthreads();
#pragma unroll
        for (int i = 0; i < 2; ++i) {
            __builtin_amdgcn_global_load_lds(
                (const __attribute__((address_space(1))) void*)(Ag + k0 + (size_t)i * 16 * K),
                (__attribute__((address_space(3))) void*)(AsW + i * 16 * 32), 16, 0, 0);
            __builtin_amdgcn_global_load_lds(
                (const __attribute__((address_space(1))) void*)(Bg + k0 + (size_t)i * 16 * K),
                (__attribute__((address_space(3))) void*)(BsW + i * 16 * 32), 16, 0, 0);
        }
        __syncthreads();

        short8 af[4], bf[4];
#pragma unroll
        for (int mt = 0; mt < 4; ++mt)
            af[mt] = *(const short8*)&As[(wm * 64 + mt * 16 + c) * 32 + quad * 8];
#pragma unroll
        for (int nt = 0; nt < 4; ++nt)
            bf[nt] = *(const short8*)&Bs[(wn * 64 + nt * 16 + c) * 32 + quad * 8];
#pragma unroll
        for (int mt = 0; mt < 4; ++mt)
#pragma unroll
            for (int nt = 0; nt < 4; ++nt)
                acc[mt][nt] = __builtin_amdgcn_mfma_f32_16x16x32_bf16(
                    af[mt], bf[nt], acc[mt][nt], 0, 0, 0);
    }

    if (EPI == 2) {
        const int g = n0 >> 7;                 // 0..31
        const int isK = g >> 4;
        const int h = g & 15;
        const float scl = isK ? 1.f : 0.125f;
        short* dst = isK ? Cb2 : Cb;           // k2 : q2, (B,H,T,128)
#pragma unroll
        for (int mt = 0; mt < 4; ++mt) {
#pragma unroll
            for (int reg = 0; reg < 4; ++reg) {
                int m = m0 + wm * 64 + mt * 16 + quad * 4 + reg;
                int bb = m >> 11, tt = m & (Tc - 1);
                size_t base = (((size_t)bb * Hc + h) * Tc + tt) * 128;
#pragma unroll
                for (int nt = 0; nt < 2; ++nt) {
                    float amp = acc[mt][nt][reg];
                    float ph  = acc[mt][nt + 2][reg];
                    int d = wn * 32 + nt * 16 + c;
                    float sp = softplusf(amp) * scl;
                    float sn, cs;
                    __sincosf(ph, &sn, &cs);
                    dst[base + d]      = f2bf(sp * cs);
                    dst[base + d + 64] = f2bf(sp * sn);
                }
            }
        }
    } else {
#pragma unroll
        for (int mt = 0; mt < 4; ++mt) {
#pragma unroll
            for (int reg = 0; reg < 4; ++reg) {
                size_t row = m0 + wm * 64 + mt * 16 + quad * 4 + reg;
#pragma unroll
                for (int nt = 0; nt < 4; ++nt) {
                    size_t col = n0 + wn * 64 + nt * 16 + c;
                    if (EPI == 1) Cb[row * N + col] = f2bf(acc[mt][nt][reg]);
                    else          Cf[row * N + col] = acc[mt][nt][reg];
                }
            }
        }
    }
}

// ---------------------------------------------------------------------------
__global__ __launch_bounds__(256) void xconv(const float* __restrict__ x,
                                             short* __restrict__ xb)
{
    int idx = blockIdx.x * 256 + threadIdx.x;
    float4 v = *(const float4*)&x[(size_t)idx * 4];
    short4 o = {f2bf(v.x), f2bf(v.y), f2bf(v.z), f2bf(v.w)};
    *(short4*)&xb[(size_t)idx * 4] = o;
}

// ---------------------------------------------------------------------------
// Wq|Wk transpose-convert with the EPI=2 row permutation.
// Source col ng (0..2047) of half z: sub = ng>>10 (amp/ph), h = (ng>>6)&15,
// d = ng&63. Dest row r = (z*16+h)*128 + (d>>5)*64 + sub*32 + (d&31).
// ---------------------------------------------------------------------------
__global__ __launch_bounds__(256) void wtrans_qk(const float* __restrict__ Wq,
                                                 const float* __restrict__ Wk,
                                                 short* __restrict__ Bt)
{
    __shared__ short tile[64][80];
    const int n0 = blockIdx.x * 64, k0 = blockIdx.y * 64;
    const int half = blockIdx.z;
    const float* W = half ? Wk : Wq;
    const int tid = threadIdx.x;
#pragma unroll
    for (int i = 0; i < 4; ++i) {
        int e = i * 256 + tid;
        int k = e >> 4, n4 = (e & 15) * 4;
        float4 v = *(const float4*)&W[(size_t)(k0 + k) * 2048 + n0 + n4];
        tile[k][n4]     = f2bf(v.x);
        tile[k][n4 + 1] = f2bf(v.y);
        tile[k][n4 + 2] = f2bf(v.z);
        tile[k][n4 + 3] = f2bf(v.w);
    }
    __syncthreads();
#pragma unroll
    for (int i = 0; i < 16; ++i) {
        int e = i * 256 + tid;
        int n = e >> 6, k = e & 63;
        int ng = n0 + n;
        int sub = ng >> 10, hh = (ng >> 6) & 15, dd = ng & 63;
        int r = (half * 16 + hh) * 128 + (dd >> 5) * 64 + sub * 32 + (dd & 31);
        Bt[(size_t)r * Cc + k0 + k] = tile[k][n];
    }
}

// ---------------------------------------------------------------------------
__global__ __launch_bounds__(256) void wtrans2(const float* __restrict__ Wv,
                                               const float* __restrict__ Wo,
                                               short* __restrict__ WtBase)
{
    __shared__ short tile[64][80];
    const int n0 = blockIdx.x * 64, k0 = blockIdx.y * 64;
    const float* W = blockIdx.z ? Wo : Wv;
    short* Wt = WtBase + (size_t)blockIdx.z * Cc * Cc;
    const int tid = threadIdx.x;
#pragma unroll
    for (int i = 0; i < 4; ++i) {
        int e = i * 256 + tid;
        int k = e >> 4, n4 = (e & 15) * 4;
        float4 v = *(const float4*)&W[(size_t)(k0 + k) * Cc + n0 + n4];
        tile[k][n4]     = f2bf(v.x);
        tile[k][n4 + 1] = f2bf(v.y);
        tile[k][n4 + 2] = f2bf(v.z);
        tile[k][n4 + 3] = f2bf(v.w);
    }
    __syncthreads();
#pragma unroll
    for (int i = 0; i < 16; ++i) {
        int e = i * 256 + tid;
        int n = e >> 6, k = e & 63;
        Wt[(size_t)(n0 + n) * Cc + k0 + k] = tile[k][n];
    }
}

// ---------------------------------------------------------------------------
__global__ __launch_bounds__(256) void vtrans_bf(const short* __restrict__ v_bf,
                                                 short* __restrict__ v2t)
{
    __shared__ __attribute__((aligned(16))) short tile[64][80];
    const int t0 = blockIdx.x * 64, h = blockIdx.y, b = blockIdx.z;
    const int tid = threadIdx.x;
#pragma unroll
    for (int i = 0; i < 2; ++i) {
        int e = i * 256 + tid;
        int t = e >> 3, d8 = (e & 7) * 8;
        *(short8*)&tile[t][d8] =
            *(const short8*)&v_bf[(size_t)(b * Tc + t0 + t) * Cc + h * Dc + d8];
    }
    __syncthreads();
#pragma unroll
    for (int i = 0; i < 16; ++i) {
        int e = i * 256 + tid;
        int d = e >> 6, t = e & 63;
        v2t[((size_t)(b * Hc + h) * Dc + d) * Tc + t0 + t] = tile[t][d];
    }
}

// ---------------------------------------------------------------------------
// MFMA flash attention v5: like v4 (512 thr / 8 waves, fixed-max softmax,
// double-buffered global_load_lds, XOR swizzle, S^T form, 1 barrier/tile)
// but the theta gate uses ONE rotating base angle per lane + 32 constant
// (cos,sin) offsets: per tile 4 rotation ops + 2 ops/element, replacing the
// 96-op per-element rotation path (R7 post-mortem: VALU-throughput bound).
// ---------------------------------------------------------------------------
__global__ __launch_bounds__(512, 4) void moire_attn5(
    const short* __restrict__ q2, const short* __restrict__ k2,
    const short* __restrict__ v2t, const float* __restrict__ theta,
    short* __restrict__ att)
{
    __shared__ __attribute__((aligned(16))) short Ks[2][64 * 128];  // 32 KB
    __shared__ __attribute__((aligned(16))) short Vt[2][64 * 64];   // 16 KB
    __shared__ __attribute__((aligned(16))) short Ps[8][16 * 64];   // 16 KB

    const int tid = threadIdx.x;
    const int wave = tid >> 6, lane = tid & 63;
    const int quad = lane >> 4, c = lane & 15;
    const int tx = wave >> 2, wq = wave & 3;
    const int p = blockIdx.x, h = blockIdx.y, b = blockIdx.z;
    const int qx = tx ? (31 - p) : p;    // this wave's q-tile
    const int q0 = qx * 64;
    const float th = theta[h];

    const short* k2b = k2 + (size_t)(b * Hc + h) * Tc * 128;
    const short* v2b = v2t + (size_t)(b * Hc + h) * Dc * Tc;

    // Q B-frags (n = t): row q0 + wq*16 + c, 4 K-chunks of 32
    short8 qf[4];
    const short* qp = q2 + ((size_t)(b * Hc + h) * Tc + q0 + wq * 16 + c) * 128;
#pragma unroll
    for (int i = 0; i < 4; ++i)
        qf[i] = *(const short8*)(qp + i * 32 + quad * 8);

    // gate*L2E = cb*cOff - sb*sOff, base (cb,sb) = angle th/8*(jt*64 - q0 - t_l)
    const int t_l = wq * 16 + c;
    float x0 = th * 0.125f * (float)(q0 + t_l);
    float cb = __cosf(x0), sb = -__sinf(x0);
    float cOff[4][4], sOff[4][4];
#pragma unroll
    for (int mt = 0; mt < 4; ++mt)
#pragma unroll
        for (int reg = 0; reg < 4; ++reg) {
            float a = th * 0.125f * (float)(mt * 16 + quad * 4 + reg);
            cOff[mt][reg] = __cosf(a) * L2E;
            sOff[mt][reg] = __sinf(a) * L2E;
        }
    const float cD = __cosf(8.f * th), sD = __sinf(8.f * th);  // 64-step rotation

    f32x4 oacc[4];
    float lsum = 0.f;
#pragma unroll
    for (int nt = 0; nt < 4; ++nt)
        oacc[nt] = (f32x4){0.f, 0.f, 0.f, 0.f};

    auto stage = [&](int jts) {
        short* KsB = &Ks[jts & 1][0];
        short* VtB = &Vt[jts & 1][0];
        const int s0 = jts * 64;
#pragma unroll
        for (int i = 0; i < 2; ++i) {          // Ks: 1024 16B chunks
            int ch = i * 512 + tid;
            int row = ch >> 4, j = ch & 15;
            const short* src = k2b + (size_t)(s0 + row) * 128 + ((j ^ (row & 15)) << 3);
            __builtin_amdgcn_global_load_lds(
                (const __attribute__((address_space(1))) void*)src,
                (__attribute__((address_space(3))) void*)(KsB + (i * 512 + wave * 64) * 8),
                16, 0, 0);
        }
        {                                       // Vt: 512 16B chunks
            int ch = tid;
            int row = ch >> 3, j = ch & 7;
            const short* src = v2b + (size_t)row * Tc + s0 + ((j ^ (row & 7)) << 3);
            __builtin_amdgcn_global_load_lds(
                (const __attribute__((address_space(1))) void*)src,
                (__attribute__((address_space(3))) void*)(VtB + (wave * 64) * 8),
                16, 0, 0);
        }
    };

    stage(0);
    const int jtEnd = 31 - p;                   // tx=1 end >= tx=0 end
    for (int jt = 0; jt <= jtEnd; ++jt) {
        __syncthreads();
        if (jt < jtEnd) stage(jt + 1);

        if (jt <= qx) {
            const short* KsB = &Ks[jt & 1][0];
            const short* VtB = &Vt[jt & 1][0];
            const bool diag = (jt == qx);

            // S^T = K Q^T : kf A-operand (m=s), qf B-operand (n=t)
            f32x4 s_acc[4];
#pragma unroll
            for (int mt = 0; mt < 4; ++mt) {
                f32x4 a = {0.f, 0.f, 0.f, 0.f};
#pragma unroll
                for (int kk = 0; kk < 4; ++kk) {
                    short8 kf = *(const short8*)&KsB[(mt * 16 + c) * 128 +
                                                     (((kk * 4 + quad) ^ c) << 3)];
                    a = __builtin_amdgcn_mfma_f32_16x16x32_bf16(kf, qf[kk], a, 0, 0, 0);
                }
                s_acc[mt] = a;
            }

            // p = exp2(s*gate*L2E - M*L2E); fixed shift M (exact softmax)
#pragma unroll
            for (int mt = 0; mt < 4; ++mt) {
                float pv[4];
#pragma unroll
                for (int reg = 0; reg < 4; ++reg) {
                    float g2 = cb * cOff[mt][reg] - sb * sOff[mt][reg];
                    float arg = fmaf(s_acc[mt][reg], g2, -SM_M * L2E);
                    if (diag && (mt * 16 + quad * 4 + reg) > t_l) arg = -1e30f;
                    pv[reg] = exp2f(arg);
                }
                lsum += (pv[0] + pv[1]) + (pv[2] + pv[3]);
                uint2 pk = {pack2bf_fast(pv[0], pv[1]), pack2bf_fast(pv[2], pv[3])};
                int slot = ((mt * 2 + (quad >> 1)) ^ (c & 7));
                *(uint2*)&Ps[wave][c * 64 + slot * 8 + (quad & 1) * 4] = pk;
            }

            // O += P V : pf A-operand (m=t) from own wave's Ps row c
            short8 pf[2];
#pragma unroll
            for (int kk = 0; kk < 2; ++kk)
                pf[kk] = *(const short8*)&Ps[wave][c * 64 +
                             (((kk * 4 + quad) ^ (c & 7)) << 3)];
#pragma unroll
            for (int nt = 0; nt < 4; ++nt)
#pragma unroll
                for (int kk = 0; kk < 2; ++kk) {
                    short8 vf = *(const short8*)&VtB[(nt * 16 + c) * 64 +
                                 (((kk * 4 + quad) ^ (c & 7)) << 3)];
                    oacc[nt] = __builtin_amdgcn_mfma_f32_16x16x32_bf16(
                        pf[kk], vf, oacc[nt], 0, 0, 0);
                }

            // advance base angle by one tile (4 ops)
            float ncb = cb * cD - sb * sD;
            sb = sb * cD + cb * sD;
            cb = ncb;
        }
    }

    // epilogue: reduce l across quads, distribute 1/l to rows, write bf16
    float l = lsum;
    l += __shfl_xor(l, 16);
    l += __shfl_xor(l, 32);
    float il = 1.f / l;
    float ilr[4];
#pragma unroll
    for (int reg = 0; reg < 4; ++reg)
        ilr[reg] = __shfl(il, quad * 4 + reg);
#pragma unroll
    for (int reg = 0; reg < 4; ++reg) {
        int t_g = q0 + wq * 16 + quad * 4 + reg;
#pragma unroll
        for (int nt = 0; nt < 4; ++nt)
            att[(size_t)(b * Tc + t_g) * Cc + h * Dc + nt * 16 + c] =
                f2bf(oacc[nt][reg] * ilr[reg]);
    }
}

// ---------------------------------------------------------------------------
extern "C" void kernel_launch(void* const* d_in, const int* in_sizes, int n_in,
                              void* d_out, int out_size, void* d_ws, size_t ws_size,
                              hipStream_t stream)
{
    const float* x     = (const float*)d_in[0];
    const float* Wq    = (const float*)d_in[1];
    const float* Wk    = (const float*)d_in[2];
    const float* Wv    = (const float*)d_in[3];
    const float* Wo    = (const float*)d_in[4];
    const float* theta = (const float*)d_in[5];
    float* out = (float*)d_out;

    const int M = Bc * Tc;                 // 4096
    char* ws = (char*)d_ws;
    const size_t MB = 1 << 20;
    short* xb   = (short*)(ws);             // [0,8)   x bf16
    short* Bqk  = (short*)(ws + 8 * MB);    // [8,16)  permuted [Wq'|Wk']^T bf16
    short* Wvt  = (short*)(ws + 16 * MB);   // [16,18)
    short* Wot  = (short*)(ws + 18 * MB);   // [18,20)
    short* v_bf = (short*)(ws + 20 * MB);   // [20,28)
    short* v2t  = (short*)(ws + 28 * MB);   // [28,36)
    short* attb = (short*)(ws + 36 * MB);   // [36,44)
    short* q2   = (short*)(ws + 44 * MB);   // [44,60) bf16 (B,H,T,128)
    short* k2   = (short*)d_out;            // 16 MB   bf16 (B,H,T,128) until final gemm

    xconv<<<(size_t)M * Cc / 1024, 256, 0, stream>>>(x, xb);
    wtrans_qk<<<dim3(2048 / 64, Cc / 64, 2), 256, 0, stream>>>(Wq, Wk, Bqk);
    wtrans2<<<dim3(Cc / 64, Cc / 64, 2), 256, 0, stream>>>(Wv, Wo, Wvt);

    // fused QK projection + moire transform (writes q2, k2 directly)
    gemm_bt_mfma<2><<<dim3(4096 / 128, M / 128), 256, 0, stream>>>(
        xb, Bqk, nullptr, q2, k2, M, 4096, Cc);
    gemm_bt_mfma<1><<<dim3(Cc / 128, M / 128), 256, 0, stream>>>(
        xb, Wvt, nullptr, v_bf, nullptr, M, Cc, Cc);

    vtrans_bf<<<dim3(Tc / 64, Hc, Bc), 256, 0, stream>>>(v_bf, v2t);

    moire_attn5<<<dim3(16, Hc, Bc), 512, 0, stream>>>(q2, k2, v2t, theta, attb);

    gemm_bt_mfma<0><<<dim3(Cc / 128, M / 128), 256, 0, stream>>>(
        attb, Wot, out, nullptr, nullptr, M, Cc, Cc);
}

// Round 9
// 263.673 us; speedup vs baseline: 2.1984x; 1.0918x over previous
//
#include <hip/hip_runtime.h>
#include <hip/hip_bf16.h>
#include <math.h>

// Problem constants
#define Bc 2
#define Tc 2048
#define Cc 1024
#define Hc 16
#define Dc 64
// SCALE = 1/8, GAMMA = 8

typedef __attribute__((ext_vector_type(8))) short short8;   // 8 bf16 (4 VGPRs)
typedef __attribute__((ext_vector_type(4))) float f32x4;    // MFMA C/D frag

#define L2E 1.44269504088896f
#define SM_M 20.0f   // fixed softmax shift; |scores| << 20 (std ~0.3)

__device__ __forceinline__ short f2bf(float x) {
    unsigned u = __float_as_uint(x);
    u += 0x7fff + ((u >> 16) & 1);      // RNE
    return (short)(u >> 16);
}
// pack two non-negative floats to bf16 pair (round-half-up) in 3 VALU ops
__device__ __forceinline__ unsigned pack2bf_fast(float a, float b) {
    unsigned ua = __float_as_uint(a) + 0x8000u;
    unsigned ub = __float_as_uint(b) + 0x8000u;
    return __builtin_amdgcn_perm(ub, ua, 0x07060302);  // (ua>>16)|(ub&0xffff0000)
}
// fast softplus: 2 HW transcendentals, ~1e-6 rel err (invisible at bf16)
__device__ __forceinline__ float softplus_fast(float a) {
    return fmaxf(a, 0.f) + __logf(1.f + __expf(-fabsf(a)));
}

// ---------------------------------------------------------------------------
// bf16 MFMA GEMM (m97 recipe): C[M,N] = A[M,K] @ Bt[N,K]^T
// EPI 0: f32 out. EPI 1: bf16 out. EPI 2: fused moire-QK epilogue.
// EPI 2 requires the Bqk row layout from wtrans_qk below: each wave's 64
// cols = [amp(h, d0..d0+31) | phase(h, d0..d0+31)], so n-tiles 0,1 are amp
// and 2,3 the matching phase IN THE SAME LANE -> no shuffle, and q2/k2
// stores are 16-lane-contiguous 32B runs (R5 post-mortem: scattered 2B
// epilogue stores caused 60x HBM write amplification; this layout avoids it).
// ---------------------------------------------------------------------------
template <int EPI>
__global__ __launch_bounds__(256) void gemm_bt_mfma(
    const short* __restrict__ A, const short* __restrict__ Bt,
    float* __restrict__ Cf, short* __restrict__ Cb, short* __restrict__ Cb2,
    int M, int N, int K)
{
    __shared__ __attribute__((aligned(16))) short As[128 * 32];
    __shared__ __attribute__((aligned(16))) short Bs[128 * 32];

    const int tid = threadIdx.x;
    const int wave = tid >> 6, lane = tid & 63;
    const int quad = lane >> 4, c = lane & 15;
    const int wm = wave >> 1, wn = wave & 1;
    const int m0 = blockIdx.y * 128, n0 = blockIdx.x * 128;

    const int srow = lane >> 2;
    const int scol = (lane & 3) * 8;
    const short* Ag = A  + (size_t)(m0 + wave * 32 + srow) * K + scol;
    const short* Bg = Bt + (size_t)(n0 + wave * 32 + srow) * K + scol;
    short* AsW = As + (wave * 32) * 32;
    short* BsW = Bs + (wave * 32) * 32;

    f32x4 acc[4][4];
#pragma unroll
    for (int i = 0; i < 4; ++i)
#pragma unroll
        for (int j = 0; j < 4; ++j)
            acc[i][j] = (f32x4){0.f, 0.f, 0.f, 0.f};

    for (int k0 = 0; k0 < K; k0 += 32) {
        __syncthreads();
#pragma unroll
        for (int i = 0; i < 2; ++i) {
            __builtin_amdgcn_global_load_lds(
                (const __attribute__((address_space(1))) void*)(Ag + k0 + (size_t)i * 16 * K),
                (__attribute__((address_space(3))) void*)(AsW + i * 16 * 32), 16, 0, 0);
            __builtin_amdgcn_global_load_lds(
                (const __attribute__((address_space(1))) void*)(Bg + k0 + (size_t)i * 16 * K),
                (__attribute__((address_space(3))) void*)(BsW + i * 16 * 32), 16, 0, 0);
        }
        __syncthreads();

        short8 af[4], bf[4];
#pragma unroll
        for (int mt = 0; mt < 4; ++mt)
            af[mt] = *(const short8*)&As[(wm * 64 + mt * 16 + c) * 32 + quad * 8];
#pragma unroll
        for (int nt = 0; nt < 4; ++nt)
            bf[nt] = *(const short8*)&Bs[(wn * 64 + nt * 16 + c) * 32 + quad * 8];
#pragma unroll
        for (int mt = 0; mt < 4; ++mt)
#pragma unroll
            for (int nt = 0; nt < 4; ++nt)
                acc[mt][nt] = __builtin_amdgcn_mfma_f32_16x16x32_bf16(
                    af[mt], bf[nt], acc[mt][nt], 0, 0, 0);
    }

    if (EPI == 2) {
        const int g = n0 >> 7;                 // 0..31
        const int isK = g >> 4;
        const int h = g & 15;
        const float scl = isK ? 1.f : 0.125f;
        short* dst = isK ? Cb2 : Cb;           // k2 : q2, (B,H,T,128)
#pragma unroll
        for (int mt = 0; mt < 4; ++mt) {
#pragma unroll
            for (int reg = 0; reg < 4; ++reg) {
                int m = m0 + wm * 64 + mt * 16 + quad * 4 + reg;
                int bb = m >> 11, tt = m & (Tc - 1);
                size_t base = (((size_t)bb * Hc + h) * Tc + tt) * 128;
#pragma unroll
                for (int nt = 0; nt < 2; ++nt) {
                    float amp = acc[mt][nt][reg];
                    float ph  = acc[mt][nt + 2][reg];
                    int d = wn * 32 + nt * 16 + c;
                    float sp = softplus_fast(amp) * scl;
                    float sn, cs;
                    __sincosf(ph, &sn, &cs);
                    dst[base + d]      = f2bf(sp * cs);
                    dst[base + d + 64] = f2bf(sp * sn);
                }
            }
        }
    } else {
#pragma unroll
        for (int mt = 0; mt < 4; ++mt) {
#pragma unroll
            for (int reg = 0; reg < 4; ++reg) {
                size_t row = m0 + wm * 64 + mt * 16 + quad * 4 + reg;
#pragma unroll
                for (int nt = 0; nt < 4; ++nt) {
                    size_t col = n0 + wn * 64 + nt * 16 + c;
                    if (EPI == 1) Cb[row * N + col] = f2bf(acc[mt][nt][reg]);
                    else          Cf[row * N + col] = acc[mt][nt][reg];
                }
            }
        }
    }
}

// ---------------------------------------------------------------------------
// V projection fused with head-transpose: v2t[(b,h,d),t] = (xb @ Wvt^T).
// Same m97 main loop; epilogue round-trips the 128x128 tile through LDS
// (pitch 136) and stores 4x256B-contiguous runs per instruction (full
// sectors -- respects the R5 write-amplification rule). M=4096,N=K=1024.
// ---------------------------------------------------------------------------
__global__ __launch_bounds__(256) void gemm_v2t(
    const short* __restrict__ A, const short* __restrict__ Bt,
    short* __restrict__ v2t)
{
    __shared__ __attribute__((aligned(16))) short As[128 * 32];
    __shared__ __attribute__((aligned(16))) short Bs[128 * 32];
    __shared__ __attribute__((aligned(16))) short tile[128 * 136];  // [n][t]

    const int K = Cc;
    const int tid = threadIdx.x;
    const int wave = tid >> 6, lane = tid & 63;
    const int quad = lane >> 4, c = lane & 15;
    const int wm = wave >> 1, wn = wave & 1;
    const int m0 = blockIdx.y * 128, n0 = blockIdx.x * 128;

    const int srow = lane >> 2;
    const int scol = (lane & 3) * 8;
    const short* Ag = A  + (size_t)(m0 + wave * 32 + srow) * K + scol;
    const short* Bg = Bt + (size_t)(n0 + wave * 32 + srow) * K + scol;
    short* AsW = As + (wave * 32) * 32;
    short* BsW = Bs + (wave * 32) * 32;

    f32x4 acc[4][4];
#pragma unroll
    for (int i = 0; i < 4; ++i)
#pragma unroll
        for (int j = 0; j < 4; ++j)
            acc[i][j] = (f32x4){0.f, 0.f, 0.f, 0.f};

    for (int k0 = 0; k0 < K; k0 += 32) {
        __syncthreads();
#pragma unroll
        for (int i = 0; i < 2; ++i) {
            __builtin_amdgcn_global_load_lds(
                (const __attribute__((address_space(1))) void*)(Ag + k0 + (size_t)i * 16 * K),
                (__attribute__((address_space(3))) void*)(AsW + i * 16 * 32), 16, 0, 0);
            __builtin_amdgcn_global_load_lds(
                (const __attribute__((address_space(1))) void*)(Bg + k0 + (size_t)i * 16 * K),
                (__attribute__((address_space(3))) void*)(BsW + i * 16 * 32), 16, 0, 0);
        }
        __syncthreads();

        short8 af[4], bf[4];
#pragma unroll
        for (int mt = 0; mt < 4; ++mt)
            af[mt] = *(const short8*)&As[(wm * 64 + mt * 16 + c) * 32 + quad * 8];
#pragma unroll
        for (int nt = 0; nt < 4; ++nt)
            bf[nt] = *(const short8*)&Bs[(wn * 64 + nt * 16 + c) * 32 + quad * 8];
#pragma unroll
        for (int mt = 0; mt < 4; ++mt)
#pragma unroll
            for (int nt = 0; nt < 4; ++nt)
                acc[mt][nt] = __builtin_amdgcn_mfma_f32_16x16x32_bf16(
                    af[mt], bf[nt], acc[mt][nt], 0, 0, 0);
    }

    // epilogue: stash transposed into LDS [n][t]
#pragma unroll
    for (int mt = 0; mt < 4; ++mt)
#pragma unroll
        for (int reg = 0; reg < 4; ++reg) {
            int tl = wm * 64 + mt * 16 + quad * 4 + reg;
#pragma unroll
            for (int nt = 0; nt < 4; ++nt)
                tile[(wn * 64 + nt * 16 + c) * 136 + tl] = f2bf(acc[mt][nt][reg]);
        }
    __syncthreads();

    const int b = m0 >> 11, tl0 = m0 & (Tc - 1);
#pragma unroll
    for (int i = 0; i < 8; ++i) {
        int n = i * 16 + (tid >> 4);
        int t8 = (tid & 15) * 8;
        int ng = n0 + n, h = ng >> 6, d = ng & 63;
        *(short8*)&v2t[(((size_t)b * Hc + h) * Dc + d) * Tc + tl0 + t8] =
            *(const short8*)&tile[n * 136 + t8];
    }
}

// ---------------------------------------------------------------------------
__global__ __launch_bounds__(256) void xconv(const float* __restrict__ x,
                                             short* __restrict__ xb)
{
    int idx = blockIdx.x * 256 + threadIdx.x;
    float4 v = *(const float4*)&x[(size_t)idx * 4];
    short4 o = {f2bf(v.x), f2bf(v.y), f2bf(v.z), f2bf(v.w)};
    *(short4*)&xb[(size_t)idx * 4] = o;
}

// ---------------------------------------------------------------------------
// Wq|Wk transpose-convert with the EPI=2 row permutation.
// Source col ng (0..2047) of half z: sub = ng>>10 (amp/ph), h = (ng>>6)&15,
// d = ng&63. Dest row r = (z*16+h)*128 + (d>>5)*64 + sub*32 + (d&31).
// ---------------------------------------------------------------------------
__global__ __launch_bounds__(256) void wtrans_qk(const float* __restrict__ Wq,
                                                 const float* __restrict__ Wk,
                                                 short* __restrict__ Bt)
{
    __shared__ short tile[64][80];
    const int n0 = blockIdx.x * 64, k0 = blockIdx.y * 64;
    const int half = blockIdx.z;
    const float* W = half ? Wk : Wq;
    const int tid = threadIdx.x;
#pragma unroll
    for (int i = 0; i < 4; ++i) {
        int e = i * 256 + tid;
        int k = e >> 4, n4 = (e & 15) * 4;
        float4 v = *(const float4*)&W[(size_t)(k0 + k) * 2048 + n0 + n4];
        tile[k][n4]     = f2bf(v.x);
        tile[k][n4 + 1] = f2bf(v.y);
        tile[k][n4 + 2] = f2bf(v.z);
        tile[k][n4 + 3] = f2bf(v.w);
    }
    __syncthreads();
#pragma unroll
    for (int i = 0; i < 16; ++i) {
        int e = i * 256 + tid;
        int n = e >> 6, k = e & 63;
        int ng = n0 + n;
        int sub = ng >> 10, hh = (ng >> 6) & 15, dd = ng & 63;
        int r = (half * 16 + hh) * 128 + (dd >> 5) * 64 + sub * 32 + (dd & 31);
        Bt[(size_t)r * Cc + k0 + k] = tile[k][n];
    }
}

// ---------------------------------------------------------------------------
__global__ __launch_bounds__(256) void wtrans2(const float* __restrict__ Wv,
                                               const float* __restrict__ Wo,
                                               short* __restrict__ WtBase)
{
    __shared__ short tile[64][80];
    const int n0 = blockIdx.x * 64, k0 = blockIdx.y * 64;
    const float* W = blockIdx.z ? Wo : Wv;
    short* Wt = WtBase + (size_t)blockIdx.z * Cc * Cc;
    const int tid = threadIdx.x;
#pragma unroll
    for (int i = 0; i < 4; ++i) {
        int e = i * 256 + tid;
        int k = e >> 4, n4 = (e & 15) * 4;
        float4 v = *(const float4*)&W[(size_t)(k0 + k) * Cc + n0 + n4];
        tile[k][n4]     = f2bf(v.x);
        tile[k][n4 + 1] = f2bf(v.y);
        tile[k][n4 + 2] = f2bf(v.z);
        tile[k][n4 + 3] = f2bf(v.w);
    }
    __syncthreads();
#pragma unroll
    for (int i = 0; i < 16; ++i) {
        int e = i * 256 + tid;
        int n = e >> 6, k = e & 63;
        Wt[(size_t)(n0 + n) * Cc + k0 + k] = tile[k][n];
    }
}

// ---------------------------------------------------------------------------
// MFMA flash attention v5 (unchanged from R8): 512 thr / 8 waves, fixed-max
// softmax, double-buffered global_load_lds, XOR swizzle, S^T form, rotating
// base-angle theta gate, 1 barrier per K-tile.
// ---------------------------------------------------------------------------
__global__ __launch_bounds__(512, 4) void moire_attn5(
    const short* __restrict__ q2, const short* __restrict__ k2,
    const short* __restrict__ v2t, const float* __restrict__ theta,
    short* __restrict__ att)
{
    __shared__ __attribute__((aligned(16))) short Ks[2][64 * 128];  // 32 KB
    __shared__ __attribute__((aligned(16))) short Vt[2][64 * 64];   // 16 KB
    __shared__ __attribute__((aligned(16))) short Ps[8][16 * 64];   // 16 KB

    const int tid = threadIdx.x;
    const int wave = tid >> 6, lane = tid & 63;
    const int quad = lane >> 4, c = lane & 15;
    const int tx = wave >> 2, wq = wave & 3;
    const int p = blockIdx.x, h = blockIdx.y, b = blockIdx.z;
    const int qx = tx ? (31 - p) : p;    // this wave's q-tile
    const int q0 = qx * 64;
    const float th = theta[h];

    const short* k2b = k2 + (size_t)(b * Hc + h) * Tc * 128;
    const short* v2b = v2t + (size_t)(b * Hc + h) * Dc * Tc;

    // Q B-frags (n = t): row q0 + wq*16 + c, 4 K-chunks of 32
    short8 qf[4];
    const short* qp = q2 + ((size_t)(b * Hc + h) * Tc + q0 + wq * 16 + c) * 128;
#pragma unroll
    for (int i = 0; i < 4; ++i)
        qf[i] = *(const short8*)(qp + i * 32 + quad * 8);

    // gate*L2E = cb*cOff - sb*sOff, base (cb,sb) = angle th/8*(jt*64 - q0 - t_l)
    const int t_l = wq * 16 + c;
    float x0 = th * 0.125f * (float)(q0 + t_l);
    float cb = __cosf(x0), sb = -__sinf(x0);
    float cOff[4][4], sOff[4][4];
#pragma unroll
    for (int mt = 0; mt < 4; ++mt)
#pragma unroll
        for (int reg = 0; reg < 4; ++reg) {
            float a = th * 0.125f * (float)(mt * 16 + quad * 4 + reg);
            cOff[mt][reg] = __cosf(a) * L2E;
            sOff[mt][reg] = __sinf(a) * L2E;
        }
    const float cD = __cosf(8.f * th), sD = __sinf(8.f * th);  // 64-step rotation

    f32x4 oacc[4];
    float lsum = 0.f;
#pragma unroll
    for (int nt = 0; nt < 4; ++nt)
        oacc[nt] = (f32x4){0.f, 0.f, 0.f, 0.f};

    auto stage = [&](int jts) {
        short* KsB = &Ks[jts & 1][0];
        short* VtB = &Vt[jts & 1][0];
        const int s0 = jts * 64;
#pragma unroll
        for (int i = 0; i < 2; ++i) {          // Ks: 1024 16B chunks
            int ch = i * 512 + tid;
            int row = ch >> 4, j = ch & 15;
            const short* src = k2b + (size_t)(s0 + row) * 128 + ((j ^ (row & 15)) << 3);
            __builtin_amdgcn_global_load_lds(
                (const __attribute__((address_space(1))) void*)src,
                (__attribute__((address_space(3))) void*)(KsB + (i * 512 + wave * 64) * 8),
                16, 0, 0);
        }
        {                                       // Vt: 512 16B chunks
            int ch = tid;
            int row = ch >> 3, j = ch & 7;
            const short* src = v2b + (size_t)row * Tc + s0 + ((j ^ (row & 7)) << 3);
            __builtin_amdgcn_global_load_lds(
                (const __attribute__((address_space(1))) void*)src,
                (__attribute__((address_space(3))) void*)(VtB + (wave * 64) * 8),
                16, 0, 0);
        }
    };

    stage(0);
    const int jtEnd = 31 - p;                   // tx=1 end >= tx=0 end
    for (int jt = 0; jt <= jtEnd; ++jt) {
        __syncthreads();
        if (jt < jtEnd) stage(jt + 1);

        if (jt <= qx) {
            const short* KsB = &Ks[jt & 1][0];
            const short* VtB = &Vt[jt & 1][0];
            const bool diag = (jt == qx);

            // S^T = K Q^T : kf A-operand (m=s), qf B-operand (n=t)
            f32x4 s_acc[4];
#pragma unroll
            for (int mt = 0; mt < 4; ++mt) {
                f32x4 a = {0.f, 0.f, 0.f, 0.f};
#pragma unroll
                for (int kk = 0; kk < 4; ++kk) {
                    short8 kf = *(const short8*)&KsB[(mt * 16 + c) * 128 +
                                                     (((kk * 4 + quad) ^ c) << 3)];
                    a = __builtin_amdgcn_mfma_f32_16x16x32_bf16(kf, qf[kk], a, 0, 0, 0);
                }
                s_acc[mt] = a;
            }

            // p = exp2(s*gate*L2E - M*L2E); fixed shift M (exact softmax)
#pragma unroll
            for (int mt = 0; mt < 4; ++mt) {
                float pv[4];
#pragma unroll
                for (int reg = 0; reg < 4; ++reg) {
                    float g2 = cb * cOff[mt][reg] - sb * sOff[mt][reg];
                    float arg = fmaf(s_acc[mt][reg], g2, -SM_M * L2E);
                    if (diag && (mt * 16 + quad * 4 + reg) > t_l) arg = -1e30f;
                    pv[reg] = exp2f(arg);
                }
                lsum += (pv[0] + pv[1]) + (pv[2] + pv[3]);
                uint2 pk = {pack2bf_fast(pv[0], pv[1]), pack2bf_fast(pv[2], pv[3])};
                int slot = ((mt * 2 + (quad >> 1)) ^ (c & 7));
                *(uint2*)&Ps[wave][c * 64 + slot * 8 + (quad & 1) * 4] = pk;
            }

            // O += P V : pf A-operand (m=t) from own wave's Ps row c
            short8 pf[2];
#pragma unroll
            for (int kk = 0; kk < 2; ++kk)
                pf[kk] = *(const short8*)&Ps[wave][c * 64 +
                             (((kk * 4 + quad) ^ (c & 7)) << 3)];
#pragma unroll
            for (int nt = 0; nt < 4; ++nt)
#pragma unroll
                for (int kk = 0; kk < 2; ++kk) {
                    short8 vf = *(const short8*)&VtB[(nt * 16 + c) * 64 +
                                 (((kk * 4 + quad) ^ (c & 7)) << 3)];
                    oacc[nt] = __builtin_amdgcn_mfma_f32_16x16x32_bf16(
                        pf[kk], vf, oacc[nt], 0, 0, 0);
                }

            // advance base angle by one tile (4 ops)
            float ncb = cb * cD - sb * sD;
            sb = sb * cD + cb * sD;
            cb = ncb;
        }
    }

    // epilogue: reduce l across quads, distribute 1/l to rows, write bf16
    float l = lsum;
    l += __shfl_xor(l, 16);
    l += __shfl_xor(l, 32);
    float il = 1.f / l;
    float ilr[4];
#pragma unroll
    for (int reg = 0; reg < 4; ++reg)
        ilr[reg] = __shfl(il, quad * 4 + reg);
#pragma unroll
    for (int reg = 0; reg < 4; ++reg) {
        int t_g = q0 + wq * 16 + quad * 4 + reg;
#pragma unroll
        for (int nt = 0; nt < 4; ++nt)
            att[(size_t)(b * Tc + t_g) * Cc + h * Dc + nt * 16 + c] =
                f2bf(oacc[nt][reg] * ilr[reg]);
    }
}

// ---------------------------------------------------------------------------
extern "C" void kernel_launch(void* const* d_in, const int* in_sizes, int n_in,
                              void* d_out, int out_size, void* d_ws, size_t ws_size,
                              hipStream_t stream)
{
    const float* x     = (const float*)d_in[0];
    const float* Wq    = (const float*)d_in[1];
    const float* Wk    = (const float*)d_in[2];
    const float* Wv    = (const float*)d_in[3];
    const float* Wo    = (const float*)d_in[4];
    const float* theta = (const float*)d_in[5];
    float* out = (float*)d_out;

    const int M = Bc * Tc;                 // 4096
    char* ws = (char*)d_ws;
    const size_t MB = 1 << 20;
    short* xb   = (short*)(ws);             // [0,8)   x bf16
    short* Bqk  = (short*)(ws + 8 * MB);    // [8,16)  permuted [Wq'|Wk']^T bf16
    short* Wvt  = (short*)(ws + 16 * MB);   // [16,18)
    short* Wot  = (short*)(ws + 18 * MB);   // [18,20)
    short* v2t  = (short*)(ws + 28 * MB);   // [28,36) bf16 (B,H,D,T)
    short* attb = (short*)(ws + 36 * MB);   // [36,44)
    short* q2   = (short*)(ws + 44 * MB);   // [44,60) bf16 (B,H,T,128)
    short* k2   = (short*)d_out;            // 16 MB   bf16 (B,H,T,128) until final gemm

    xconv<<<(size_t)M * Cc / 1024, 256, 0, stream>>>(x, xb);
    wtrans_qk<<<dim3(2048 / 64, Cc / 64, 2), 256, 0, stream>>>(Wq, Wk, Bqk);
    wtrans2<<<dim3(Cc / 64, Cc / 64, 2), 256, 0, stream>>>(Wv, Wo, Wvt);

    // fused QK projection + moire transform (writes q2, k2 directly)
    gemm_bt_mfma<2><<<dim3(4096 / 128, M / 128), 256, 0, stream>>>(
        xb, Bqk, nullptr, q2, k2, M, 4096, Cc);
    // fused V projection + head-transpose (writes v2t directly)
    gemm_v2t<<<dim3(Cc / 128, M / 128), 256, 0, stream>>>(xb, Wvt, v2t);

    moire_attn5<<<dim3(16, Hc, Bc), 512, 0, stream>>>(q2, k2, v2t, theta, attb);

    gemm_bt_mfma<0><<<dim3(Cc / 128, M / 128), 256, 0, stream>>>(
        attb, Wot, out, nullptr, nullptr, M, Cc, Cc);
}